// Round 10
// baseline (82.818 us; speedup 1.0000x reference)
//
#include <hip/hip_runtime.h>
#include <math.h>

#define S_LEN 2048
#define B_SZ 2
#define NH 8
#define DH 64
#define DM 512
#define MROWS 4096  // B*S

typedef __attribute__((ext_vector_type(8))) short s16x8;
typedef __attribute__((ext_vector_type(4))) float fx4;
typedef __attribute__((ext_vector_type(16))) float fx16;
typedef __attribute__((ext_vector_type(4))) int ix4;
typedef __attribute__((ext_vector_type(2))) int ix2;

__device__ inline short f2bf(float x){
  unsigned u = __float_as_uint(x);
  u = (u + 0x7FFFu + ((u >> 16) & 1u)) >> 16;
  return (short)u;
}

__device__ inline fx4 mfma16(s16x8 a, s16x8 b, fx4 c){
  return __builtin_amdgcn_mfma_f32_16x16x32_bf16(a, b, c, 0, 0, 0);
}
__device__ inline fx16 mfma32(s16x8 a, s16x8 b, fx16 c){
  return __builtin_amdgcn_mfma_f32_32x32x16_bf16(a, b, c, 0, 0, 0);
}
__device__ inline int cvtpk(float a, float b){
  int r; asm("v_cvt_pk_bf16_f32 %0, %1, %2" : "=v"(r) : "v"(a), "v"(b)); return r;
}

#define GLL16(g, l) __builtin_amdgcn_global_load_lds((const __attribute__((address_space(1))) void*)(g), (__attribute__((address_space(3))) void*)(l), 16, 0, 0)
#define GLL4(g, l)  __builtin_amdgcn_global_load_lds((const __attribute__((address_space(1))) void*)(g), (__attribute__((address_space(3))) void*)(l), 4, 0, 0)

// ---- K0: fused weight-transpose (blocks 0..255) + logmap (blocks 256..1279) ----
__global__ __launch_bounds__(256) void prep_kernel(const float* __restrict__ W0,
                                                   const float* __restrict__ W1,
                                                   const float* __restrict__ W2,
                                                   const float* __restrict__ W3,
                                                   short* __restrict__ Wt,
                                                   const float* __restrict__ x,
                                                   short* __restrict__ xeu){
  __shared__ short tile[64][66];
  int bid = blockIdx.x;
  int t = threadIdx.x;
  if (bid < 256){
    int z = bid >> 6, rem = bid & 63;
    const float* W = (z == 0) ? W0 : (z == 1) ? W1 : (z == 2) ? W2 : W3;
    short* Wtz = Wt + (size_t)z * DM * DM;
    int n0 = (rem & 7) * 64, k0 = (rem >> 3) * 64;
    int nl = t & 63;
    #pragma unroll
    for (int p = 0; p < 16; ++p){
      int kl = (t >> 6) + p * 4;
      tile[kl][nl] = f2bf(W[(size_t)(k0 + kl) * DM + n0 + nl]);
    }
    __syncthreads();
    int kl2 = t & 63;
    #pragma unroll
    for (int p = 0; p < 16; ++p){
      int nl2 = (t >> 6) + p * 4;
      Wtz[(size_t)(n0 + nl2) * DM + k0 + kl2] = tile[kl2][nl2];
    }
  } else {
    int row = (bid - 256) * 4 + (t >> 6);
    int lane = t & 63;
    const float* xr = x + (size_t)row * (DM + 1);
    float v[8]; float ss = 0.f;
    #pragma unroll
    for (int j = 0; j < 8; ++j){
      v[j] = xr[1 + lane * 8 + j];
      ss += v[j] * v[j];
    }
    #pragma unroll
    for (int off = 1; off < 64; off <<= 1) ss += __shfl_xor(ss, off);
    float nrm = sqrtf(ss);
    float theta = acoshf(fmaxf(xr[0], 1.0f + 1e-7f));
    float scl = theta / fmaxf(nrm, 1e-7f);
    s16x8 pk;
    #pragma unroll
    for (int j = 0; j < 8; ++j) pk[j] = f2bf(scl * v[j]);
    *(s16x8*)(xeu + (size_t)row * DM + lane * 8) = pk;
  }
}

// ---- K2: QKV GEMM 128x128 tiles (wave = one head) + fused exp-map / V-transpose ----
__global__ __launch_bounds__(256, 2) void gemm_fused_kernel(const short* __restrict__ A,
                                                            const short* __restrict__ Bt,
                                                            const float* __restrict__ labsK,
                                                            float* __restrict__ Qt,
                                                            short* __restrict__ Qs,
                                                            float* __restrict__ Kt,
                                                            short* __restrict__ Ks,
                                                            short* __restrict__ Vt){
  __shared__ __attribute__((aligned(16))) short Stage[4][8192]; // [0..1]=A, [2..3]=B
  const int K = DM;
  int z = blockIdx.z;
  int hp = blockIdx.y;                // head pair
  int n0 = hp * 128, m0 = blockIdx.x * 128;
  int t = threadIdx.x;
  int w = t >> 6, lane = t & 63;
  int wm = w >> 1, wn = w & 1;
  int lg = lane >> 4, lr = lane & 15;
  const short* Btz = Bt + (size_t)z * K * DM;

  int coff[4]; const short* asrcp[4]; const short* bsrcp[4];
  #pragma unroll
  for (int j = 0; j < 4; ++j){
    int ch = t + 256 * j;
    int r = ch >> 3, c = ch & 7;
    coff[j] = ch * 8;
    asrcp[j] = A   + (size_t)(m0 + r) * K + 8 * (c ^ (r & 7));
    bsrcp[j] = Btz + (size_t)(n0 + r) * K + 8 * (c ^ (r & 7));
  }

  #pragma unroll
  for (int j = 0; j < 4; ++j){
    GLL16(asrcp[j], &Stage[0][coff[j]]);
    GLL16(bsrcp[j], &Stage[2][coff[j]]);
  }

  fx4 acc[4][4] = {};
  for (int ks = 0; ks < 8; ++ks){
    asm volatile("s_waitcnt vmcnt(0)" ::: "memory");
    __builtin_amdgcn_s_barrier();
    if (ks < 7){
      int nb = (ks + 1) & 1;
      int kk = (ks + 1) * 64;
      #pragma unroll
      for (int j = 0; j < 4; ++j){
        GLL16(asrcp[j] + kk, &Stage[nb][coff[j]]);
        GLL16(bsrcp[j] + kk, &Stage[2 + nb][coff[j]]);
      }
    }
    int buf = ks & 1;
    s16x8 af[4][2], bf[4][2];
    #pragma unroll
    for (int mi = 0; mi < 4; ++mi){
      int row = wm * 64 + mi * 16 + lr;
      #pragma unroll
      for (int s = 0; s < 2; ++s)
        af[mi][s] = *(const s16x8*)&Stage[buf][row * 64 + ((4 * s + lg) ^ (row & 7)) * 8];
    }
    #pragma unroll
    for (int ni = 0; ni < 4; ++ni){
      int row = wn * 64 + ni * 16 + lr;
      #pragma unroll
      for (int s = 0; s < 2; ++s)
        bf[ni][s] = *(const s16x8*)&Stage[2 + buf][row * 64 + ((4 * s + lg) ^ (row & 7)) * 8];
    }
    __builtin_amdgcn_s_setprio(1);
    #pragma unroll
    for (int s = 0; s < 2; ++s)
      #pragma unroll
      for (int mi = 0; mi < 4; ++mi)
        #pragma unroll
        for (int ni = 0; ni < 4; ++ni)
          acc[mi][ni] = mfma16(af[mi][s], bf[ni][s], acc[mi][ni]);
    __builtin_amdgcn_s_setprio(0);
  }

  int h = hp * 2 + wn;                // this wave's head
  if (z < 2){
    float c  = __expf(labsK[h]);
    float sc = sqrtf(c);
    float invsc = __frcp_rn(sc);
    float a  = 0.125f * c * 1.4426950408889634f;
    float tmul = (z == 0) ? a : 1.0f;
    float vmul = (z == 0) ? -a : 1.0f;
    float* Tt = (z == 0) ? Qt : Kt;
    short* Ts = (z == 0) ? Qs : Ks;
    #pragma unroll
    for (int mi = 0; mi < 4; ++mi)
      #pragma unroll
      for (int r = 0; r < 4; ++r){
        float prt = 0.f;
        #pragma unroll
        for (int ni = 0; ni < 4; ++ni) prt += acc[mi][ni][r] * acc[mi][ni][r];
        prt += __shfl_xor(prt, 1);
        prt += __shfl_xor(prt, 2);
        prt += __shfl_xor(prt, 4);
        prt += __shfl_xor(prt, 8);
        float n = fmaxf(sqrtf(prt), 1e-7f);
        float arg = sc * n;
        float e = __expf(arg), ei = __frcp_rn(e);
        float tval = tmul * 0.5f * (e + ei) * invsc;
        float vscl = vmul * 0.5f * (e - ei) * __frcp_rn(arg);
        int grow = m0 + wm * 64 + mi * 16 + 4 * lg + r;
        int b = grow >> 11, s = grow & (S_LEN - 1);
        size_t bhs = ((size_t)(b * NH + h) * S_LEN + s);
        if (lr == 0) Tt[bhs] = tval;
        #pragma unroll
        for (int ni = 0; ni < 4; ++ni)
          Ts[bhs * DH + ni * 16 + lr] = f2bf(vscl * acc[mi][ni][r]);
      }
  } else {
    __syncthreads();                 // all waves done reading Stage
    short* vt = &Stage[0][0] + w * 4352;   // per-wave 64x68
    #pragma unroll
    for (int mi = 0; mi < 4; ++mi)
      #pragma unroll
      for (int ni = 0; ni < 4; ++ni)
        #pragma unroll
        for (int r = 0; r < 4; ++r)
          vt[(ni * 16 + lr) * 68 + mi * 16 + 4 * lg + r] = f2bf(acc[mi][ni][r]);
    int b = m0 >> 11;
    int sglob = (m0 & (S_LEN - 1)) + wm * 64;
    size_t vbase = ((size_t)(b * NH + h) * DH + lane) * S_LEN + sglob;
    #pragma unroll
    for (int j = 0; j < 8; ++j){
      s16x8 val = *(const s16x8*)&vt[lane * 68 + j * 8];
      *(s16x8*)(Vt + vbase + j * 8) = val;
    }
  }
}

// ---- K4: flash attention, NO key-split. 512 blocks x 2 waves, 64 q each,
//      full causal range, longest-first, direct Obf write. ----
__global__ __launch_bounds__(128, 2) void attn_kernel(const short* __restrict__ Qs,
                                                      const float* __restrict__ Qt,
                                                      const short* __restrict__ Ks,
                                                      const float* __restrict__ Kt,
                                                      const short* __restrict__ Vt,
                                                      short* __restrict__ Obf){
  __shared__ __attribute__((aligned(16))) short Ksm[3][4096];
  __shared__ __attribute__((aligned(16))) short Vsm[3][4096];
  __shared__ __attribute__((aligned(16))) float Ktm[3][64];

  int bx = blockIdx.x;
  int bh = bx & 15;                  // XCD-local heads
  int g  = 31 - (bx >> 4);           // longest blocks dispatched first
  int ntc = g + 1;

  int tid = threadIdx.x;
  int w = tid >> 6, lane = tid & 63;
  int l5 = lane & 31, hi = lane >> 5;
  size_t bhS = (size_t)bh * S_LEN;

  const short* Kg  = Ks + bhS * DH;
  const short* Vg  = Vt + (size_t)bh * DH * S_LEN;
  const float* Ktg = Kt + bhS;

  int srow = lane >> 3;
  int scol = ((lane & 7) * 8) ^ (srow << 3);
  const short* kgA = Kg + (size_t)(32 * w + srow) * DH + scol;
  const short* vgA = Vg + (size_t)(32 * w + srow) * S_LEN + scol;
  const float* ktg = Ktg + lane;

  int q0w = 64 * g + 32 * w;
  int q   = q0w + l5;
  s16x8 qf[4];
  #pragma unroll
  for (int dblk = 0; dblk < 4; ++dblk)
    qf[dblk] = *(const s16x8*)(Qs + (bhS + q) * DH + dblk * 16 + hi * 8);
  float aqt = Qt[bhS + q];

  fx16 acc0, acc1;
  #pragma unroll
  for (int i = 0; i < 16; ++i){ acc0[i] = 0.f; acc1[i] = 0.f; }
  float mrun = 0.f, lrun = 0.f;

  // per-wave staging: 4 x K-rows (32 each) + 4 x V-rows + (w==1) Kt
  #define STAGE_T(tt, b) { int off_ = (tt) * 64; \
    GLL16(kgA + (size_t)off_ * DH,           &Ksm[b][(32 * w +  0) * 64]); \
    GLL16(kgA + (size_t)off_ * DH +  8 * DH, &Ksm[b][(32 * w +  8) * 64]); \
    GLL16(kgA + (size_t)off_ * DH + 16 * DH, &Ksm[b][(32 * w + 16) * 64]); \
    GLL16(kgA + (size_t)off_ * DH + 24 * DH, &Ksm[b][(32 * w + 24) * 64]); \
    GLL16(vgA + off_,              &Vsm[b][(32 * w +  0) * 64]); \
    GLL16(vgA + off_ +  8 * S_LEN, &Vsm[b][(32 * w +  8) * 64]); \
    GLL16(vgA + off_ + 16 * S_LEN, &Vsm[b][(32 * w + 16) * 64]); \
    GLL16(vgA + off_ + 24 * S_LEN, &Vsm[b][(32 * w + 24) * 64]); \
    if (w == 1) GLL4(ktg + off_, &Ktm[b][0]); }

  STAGE_T(0, 0);
  if (ntc > 1) STAGE_T(1, 1);

  int buf = 0, sbuf = 2;
  for (int t = 0; t < ntc; ++t){
    int k0 = t * 64;
    if (t + 1 < ntc){
      if (w == 1) asm volatile("s_waitcnt vmcnt(9)" ::: "memory");
      else        asm volatile("s_waitcnt vmcnt(8)" ::: "memory");
    } else {
      asm volatile("s_waitcnt vmcnt(0)" ::: "memory");
    }
    __builtin_amdgcn_s_barrier();
    if (t + 2 < ntc) STAGE_T(t + 2, sbuf);

    {
      fx16 st[2];
      __builtin_amdgcn_s_setprio(1);
      #pragma unroll
      for (int s = 0; s < 2; ++s){
        const short* kb = &Ksm[buf][(32 * s + l5) * 64];
        fx16 z;
        #pragma unroll
        for (int i = 0; i < 16; ++i) z[i] = 0.f;
        #pragma unroll
        for (int dblk = 0; dblk < 4; ++dblk){
          s16x8 kf = *(const s16x8*)(kb + ((16 * dblk + 8 * hi) ^ ((l5 & 7) << 3)));
          z = mfma32(kf, qf[dblk], z);
        }
        st[s] = z;
      }
      __builtin_amdgcn_s_setprio(0);
      float p[2][16];
      #pragma unroll
      for (int s = 0; s < 2; ++s)
        #pragma unroll
        for (int m4 = 0; m4 < 4; ++m4){
          fx4 kt4 = *(const fx4*)&Ktm[buf][32 * s + 8 * m4 + 4 * hi];
          #pragma unroll
          for (int tt = 0; tt < 4; ++tt)
            p[s][4 * m4 + tt] = st[s][4 * m4 + tt] + aqt * kt4[tt];
        }
      if (k0 + 63 > q0w){
        #pragma unroll
        for (int s = 0; s < 2; ++s)
          #pragma unroll
          for (int r = 0; r < 16; ++r){
            int kg2 = k0 + 32 * s + (r & 3) + 8 * (r >> 2) + 4 * hi;
            if (kg2 > q) p[s][r] = -3e38f;
          }
      }
      float v16[16];
      #pragma unroll
      for (int i = 0; i < 16; ++i) v16[i] = fmaxf(p[0][i], p[1][i]);
      #pragma unroll
      for (int i = 0; i < 8; ++i) v16[i] = fmaxf(v16[i], v16[i + 8]);
      #pragma unroll
      for (int i = 0; i < 4; ++i) v16[i] = fmaxf(v16[i], v16[i + 4]);
      float pmax = fmaxf(fmaxf(v16[0], v16[1]), fmaxf(v16[2], v16[3]));
      pmax = fmaxf(pmax, __shfl_xor(pmax, 32));
      if (!__all(pmax <= mrun + 8.f)){
        float mnew = fmaxf(mrun, pmax);
        float scl = __builtin_amdgcn_exp2f(mrun - mnew);
        mrun = mnew;
        lrun *= scl;
        #pragma unroll
        for (int i = 0; i < 16; ++i){ acc0[i] *= scl; acc1[i] *= scl; }
      }
      float sm[16];
      #pragma unroll
      for (int i = 0; i < 16; ++i){
        p[0][i] = __builtin_amdgcn_exp2f(p[0][i] - mrun);
        p[1][i] = __builtin_amdgcn_exp2f(p[1][i] - mrun);
        sm[i] = p[0][i] + p[1][i];
      }
      #pragma unroll
      for (int i = 0; i < 8; ++i) sm[i] += sm[i + 8];
      #pragma unroll
      for (int i = 0; i < 4; ++i) sm[i] += sm[i + 4];
      float rsum = (sm[0] + sm[1]) + (sm[2] + sm[3]);
      rsum += __shfl_xor(rsum, 32);
      lrun += rsum;

      #pragma unroll
      for (int h2 = 0; h2 < 4; ++h2){
        int s = h2 >> 1, hb = h2 & 1;
        int w0 = cvtpk(p[s][8 * hb + 0], p[s][8 * hb + 1]);
        int w1 = cvtpk(p[s][8 * hb + 2], p[s][8 * hb + 3]);
        int w2 = cvtpk(p[s][8 * hb + 4], p[s][8 * hb + 5]);
        int w3 = cvtpk(p[s][8 * hb + 6], p[s][8 * hb + 7]);
        int sdA = hi ? w0 : w2;
        int sdB = hi ? w1 : w3;
        int rcA = __shfl_xor(sdA, 32);
        int rcB = __shfl_xor(sdB, 32);
        ix4 fw;
        fw.x = hi ? rcA : w0; fw.y = hi ? rcB : w1;
        fw.z = hi ? w2 : rcA; fw.w = hi ? w3 : rcB;
        s16x8 pf = __builtin_bit_cast(s16x8, fw);
        const short* vb0 = &Vsm[buf][(l5) * 64 + ((16 * h2 + 8 * hi) ^ ((l5 & 7) << 3))];
        const short* vb1 = vb0 + 32 * 64;
        s16x8 vf0 = *(const s16x8*)vb0;
        s16x8 vf1 = *(const s16x8*)vb1;
        __builtin_amdgcn_s_setprio(1);
        acc0 = mfma32(vf0, pf, acc0);
        acc1 = mfma32(vf1, pf, acc1);
        __builtin_amdgcn_s_setprio(0);
      }
    }
    buf  = (buf == 2)  ? 0 : buf + 1;
    sbuf = (sbuf == 2) ? 0 : sbuf + 1;
  }
  #undef STAGE_T

  // ---- epilogue: O = acc/l, direct bf16 store ----
  float invl = 1.0f / lrun;
  int qi = 32 * w + l5;
  int bb = bh >> 3, hh = bh & 7;
  short* orow = Obf + ((size_t)bb * S_LEN + 64 * g + qi) * DM + hh * DH;
  #pragma unroll
  for (int j = 0; j < 4; ++j){
    ix2 v0, v1;
    v0.x = cvtpk(acc0[4 * j + 0] * invl, acc0[4 * j + 1] * invl);
    v0.y = cvtpk(acc0[4 * j + 2] * invl, acc0[4 * j + 3] * invl);
    v1.x = cvtpk(acc1[4 * j + 0] * invl, acc1[4 * j + 1] * invl);
    v1.y = cvtpk(acc1[4 * j + 2] * invl, acc1[4 * j + 3] * invl);
    *(ix2*)(orow + 8 * j + 4 * hi)      = v0;
    *(ix2*)(orow + 32 + 8 * j + 4 * hi) = v1;
  }
}

// ---- K5: O-projection GEMM, 64x64 tiles, single-barrier loop ----
__global__ __launch_bounds__(256, 4) void gemm_o_kernel(const short* __restrict__ A,
                                                        const short* __restrict__ Bt,
                                                        float* __restrict__ C){
  __shared__ __attribute__((aligned(16))) short Asm[2][64 * 64];
  __shared__ __attribute__((aligned(16))) short Bsm[2][64 * 64];
  const int K = DM;
  int n0 = blockIdx.y * 64, m0 = blockIdx.x * 64;
  int t = threadIdx.x;
  int w = t >> 6, lane = t & 63;
  int wm = w >> 1, wn = w & 1;
  int lg = lane >> 4, lr = lane & 15;

  int aoff[2]; const short* asrcp[2];
  int boff[2]; const short* bsrcp[2];
  #pragma unroll
  for (int j = 0; j < 2; ++j){
    int ch = t + 256 * j;
    int r = ch >> 3, c = ch & 7;
    aoff[j] = ch * 8;
    asrcp[j] = A + (size_t)(m0 + r) * K + 8 * (c ^ (r & 7));
    boff[j] = ch * 8;
    bsrcp[j] = Bt + (size_t)(n0 + r) * K + 8 * (c ^ (r & 7));
  }

  {
    short* ab = &Asm[0][0]; short* bb = &Bsm[0][0];
    #pragma unroll
    for (int j = 0; j < 2; ++j){ GLL16(asrcp[j], ab + aoff[j]); GLL16(bsrcp[j], bb + boff[j]); }
  }

  fx4 acc[2][2] = {};
  for (int ks = 0; ks < 8; ++ks){
    asm volatile("s_waitcnt vmcnt(0)" ::: "memory");
    __builtin_amdgcn_s_barrier();
    if (ks < 7){
      int nb = (ks + 1) & 1;
      short* ab = &Asm[nb][0]; short* bb = &Bsm[nb][0];
      int kk = (ks + 1) * 64;
      #pragma unroll
      for (int j = 0; j < 2; ++j){ GLL16(asrcp[j] + kk, ab + aoff[j]); GLL16(bsrcp[j] + kk, bb + boff[j]); }
    }
    int buf = ks & 1;
    s16x8 af[2][2], bf[2][2];
    #pragma unroll
    for (int mi = 0; mi < 2; ++mi){
      int row = wm * 32 + mi * 16 + lr;
      #pragma unroll
      for (int s = 0; s < 2; ++s)
        af[mi][s] = *(const s16x8*)&Asm[buf][row * 64 + ((4 * s + lg) ^ (row & 7)) * 8];
    }
    #pragma unroll
    for (int ni = 0; ni < 2; ++ni){
      int row = wn * 32 + ni * 16 + lr;
      #pragma unroll
      for (int s = 0; s < 2; ++s)
        bf[ni][s] = *(const s16x8*)&Bsm[buf][row * 64 + ((4 * s + lg) ^ (row & 7)) * 8];
    }
    __builtin_amdgcn_s_setprio(1);
    #pragma unroll
    for (int s = 0; s < 2; ++s)
      #pragma unroll
      for (int mi = 0; mi < 2; ++mi)
        #pragma unroll
        for (int ni = 0; ni < 2; ++ni)
          acc[mi][ni] = mfma16(af[mi][s], bf[ni][s], acc[mi][ni]);
    __builtin_amdgcn_s_setprio(0);
  }

  #pragma unroll
  for (int mi = 0; mi < 2; ++mi)
    #pragma unroll
    for (int ni = 0; ni < 2; ++ni)
      #pragma unroll
      for (int r = 0; r < 4; ++r){
        int row = m0 + wm * 32 + mi * 16 + 4 * lg + r;
        int col = n0 + wn * 32 + ni * 16 + lr;
        C[(size_t)row * DM + col] = acc[mi][ni][r];
      }
}

extern "C" void kernel_launch(void* const* d_in, const int* in_sizes, int n_in,
                              void* d_out, int out_size, void* d_ws, size_t ws_size,
                              hipStream_t stream) {
  const float* x     = (const float*)d_in[0];
  const float* Wq    = (const float*)d_in[1];
  const float* Wk    = (const float*)d_in[2];
  const float* Wv    = (const float*)d_in[3];
  const float* Wo    = (const float*)d_in[4];
  const float* labsK = (const float*)d_in[5];

  char* w = (char*)d_ws;
  short* Wt    = (short*)(w);                                  // 2 MB
  short* xeu   = (short*)(w + (2ull  << 20));                  // 4 MB
  short* Qs    = (short*)(w + (30ull << 20));                  // 4 MB
  short* Ks    = (short*)(w + (34ull << 20));                  // 4 MB
  short* Vt    = (short*)(w + (38ull << 20));                  // 4 MB
  float* Qt    = (float*)(w + (42ull << 20));                  // 128 KB
  float* Kt    = (float*)(w + (42ull << 20) + (128ull << 10)); // 128 KB
  short* Obf   = (short*)(w + (42ull << 20) + (256ull << 10)); // 4 MB

  prep_kernel<<<dim3(1280), 256, 0, stream>>>(Wq, Wk, Wv, Wo, Wt, x, xeu);

  gemm_fused_kernel<<<dim3(32, 4, 3), 256, 0, stream>>>(
      xeu, Wt, labsK, Qt, Qs, Kt, Ks, Vt);

  attn_kernel<<<dim3(512), 128, 0, stream>>>(Qs, Qt, Ks, Kt, Vt, Obf);

  gemm_o_kernel<<<dim3(64, 8), 256, 0, stream>>>(Obf, Wt + 3 * DM * DM, (float*)d_out);
}

// Round 12
// 60.607 us; speedup vs baseline: 1.3665x; 1.3665x over previous
//
#include <hip/hip_runtime.h>
#include <math.h>

#define S_LEN 2048
#define B_SZ 2
#define NH 8
#define DH 64
#define DM 512
#define MROWS 4096  // B*S

typedef __attribute__((ext_vector_type(8))) short s16x8;
typedef __attribute__((ext_vector_type(4))) float fx4;
typedef __attribute__((ext_vector_type(16))) float fx16;
typedef __attribute__((ext_vector_type(4))) int ix4;
typedef __attribute__((ext_vector_type(2))) int ix2;

__device__ inline short f2bf(float x){
  unsigned u = __float_as_uint(x);
  u = (u + 0x7FFFu + ((u >> 16) & 1u)) >> 16;
  return (short)u;
}
__device__ inline float bf2f(short s){
  return __uint_as_float(((unsigned)(unsigned short)s) << 16);
}

__device__ inline fx4 mfma16(s16x8 a, s16x8 b, fx4 c){
  return __builtin_amdgcn_mfma_f32_16x16x32_bf16(a, b, c, 0, 0, 0);
}
__device__ inline fx16 mfma32(s16x8 a, s16x8 b, fx16 c){
  return __builtin_amdgcn_mfma_f32_32x32x16_bf16(a, b, c, 0, 0, 0);
}
__device__ inline int cvtpk(float a, float b){
  int r; asm("v_cvt_pk_bf16_f32 %0, %1, %2" : "=v"(r) : "v"(a), "v"(b)); return r;
}

#define GLL16(g, l) __builtin_amdgcn_global_load_lds((const __attribute__((address_space(1))) void*)(g), (__attribute__((address_space(3))) void*)(l), 16, 0, 0)
#define GLL4(g, l)  __builtin_amdgcn_global_load_lds((const __attribute__((address_space(1))) void*)(g), (__attribute__((address_space(3))) void*)(l), 4, 0, 0)

// ---- K0: fused weight-transpose (blocks 0..255) + logmap (blocks 256..1279) ----
__global__ __launch_bounds__(256) void prep_kernel(const float* __restrict__ W0,
                                                   const float* __restrict__ W1,
                                                   const float* __restrict__ W2,
                                                   const float* __restrict__ W3,
                                                   short* __restrict__ Wt,
                                                   const float* __restrict__ x,
                                                   short* __restrict__ xeu){
  __shared__ short tile[64][66];
  int bid = blockIdx.x;
  int t = threadIdx.x;
  if (bid < 256){
    int z = bid >> 6, rem = bid & 63;
    const float* W = (z == 0) ? W0 : (z == 1) ? W1 : (z == 2) ? W2 : W3;
    short* Wtz = Wt + (size_t)z * DM * DM;
    int n0 = (rem & 7) * 64, k0 = (rem >> 3) * 64;
    int nl = t & 63;
    #pragma unroll
    for (int p = 0; p < 16; ++p){
      int kl = (t >> 6) + p * 4;
      tile[kl][nl] = f2bf(W[(size_t)(k0 + kl) * DM + n0 + nl]);
    }
    __syncthreads();
    int kl2 = t & 63;
    #pragma unroll
    for (int p = 0; p < 16; ++p){
      int nl2 = (t >> 6) + p * 4;
      Wtz[(size_t)(n0 + nl2) * DM + k0 + kl2] = tile[kl2][nl2];
    }
  } else {
    int row = (bid - 256) * 4 + (t >> 6);
    int lane = t & 63;
    const float* xr = x + (size_t)row * (DM + 1);
    float v[8]; float ss = 0.f;
    #pragma unroll
    for (int j = 0; j < 8; ++j){
      v[j] = xr[1 + lane * 8 + j];
      ss += v[j] * v[j];
    }
    #pragma unroll
    for (int off = 1; off < 64; off <<= 1) ss += __shfl_xor(ss, off);
    float nrm = sqrtf(ss);
    float theta = acoshf(fmaxf(xr[0], 1.0f + 1e-7f));
    float scl = theta / fmaxf(nrm, 1e-7f);
    s16x8 pk;
    #pragma unroll
    for (int j = 0; j < 8; ++j) pk[j] = f2bf(scl * v[j]);
    *(s16x8*)(xeu + (size_t)row * DM + lane * 8) = pk;
  }
}

// ---- K2: QKV GEMM 128x128 tiles (wave = one head) + fused exp-map / V-transpose ----
__global__ __launch_bounds__(256, 2) void gemm_fused_kernel(const short* __restrict__ A,
                                                            const short* __restrict__ Bt,
                                                            const float* __restrict__ labsK,
                                                            float* __restrict__ Qt,
                                                            short* __restrict__ Qs,
                                                            float* __restrict__ Kt,
                                                            short* __restrict__ Ks,
                                                            short* __restrict__ Vt){
  __shared__ __attribute__((aligned(16))) short Stage[4][8192]; // [0..1]=A, [2..3]=B
  const int K = DM;
  int z = blockIdx.z;
  int hp = blockIdx.y;                // head pair
  int n0 = hp * 128, m0 = blockIdx.x * 128;
  int t = threadIdx.x;
  int w = t >> 6, lane = t & 63;
  int wm = w >> 1, wn = w & 1;
  int lg = lane >> 4, lr = lane & 15;
  const short* Btz = Bt + (size_t)z * K * DM;

  int coff[4]; const short* asrcp[4]; const short* bsrcp[4];
  #pragma unroll
  for (int j = 0; j < 4; ++j){
    int ch = t + 256 * j;
    int r = ch >> 3, c = ch & 7;
    coff[j] = ch * 8;
    asrcp[j] = A   + (size_t)(m0 + r) * K + 8 * (c ^ (r & 7));
    bsrcp[j] = Btz + (size_t)(n0 + r) * K + 8 * (c ^ (r & 7));
  }

  #pragma unroll
  for (int j = 0; j < 4; ++j){
    GLL16(asrcp[j], &Stage[0][coff[j]]);
    GLL16(bsrcp[j], &Stage[2][coff[j]]);
  }

  fx4 acc[4][4] = {};
  for (int ks = 0; ks < 8; ++ks){
    asm volatile("s_waitcnt vmcnt(0)" ::: "memory");
    __builtin_amdgcn_s_barrier();
    if (ks < 7){
      int nb = (ks + 1) & 1;
      int kk = (ks + 1) * 64;
      #pragma unroll
      for (int j = 0; j < 4; ++j){
        GLL16(asrcp[j] + kk, &Stage[nb][coff[j]]);
        GLL16(bsrcp[j] + kk, &Stage[2 + nb][coff[j]]);
      }
    }
    int buf = ks & 1;
    s16x8 af[4][2], bf[4][2];
    #pragma unroll
    for (int mi = 0; mi < 4; ++mi){
      int row = wm * 64 + mi * 16 + lr;
      #pragma unroll
      for (int s = 0; s < 2; ++s)
        af[mi][s] = *(const s16x8*)&Stage[buf][row * 64 + ((4 * s + lg) ^ (row & 7)) * 8];
    }
    #pragma unroll
    for (int ni = 0; ni < 4; ++ni){
      int row = wn * 64 + ni * 16 + lr;
      #pragma unroll
      for (int s = 0; s < 2; ++s)
        bf[ni][s] = *(const s16x8*)&Stage[2 + buf][row * 64 + ((4 * s + lg) ^ (row & 7)) * 8];
    }
    __builtin_amdgcn_s_setprio(1);
    #pragma unroll
    for (int s = 0; s < 2; ++s)
      #pragma unroll
      for (int mi = 0; mi < 4; ++mi)
        #pragma unroll
        for (int ni = 0; ni < 4; ++ni)
          acc[mi][ni] = mfma16(af[mi][s], bf[ni][s], acc[mi][ni]);
    __builtin_amdgcn_s_setprio(0);
  }

  int h = hp * 2 + wn;                // this wave's head
  if (z < 2){
    float c  = __expf(labsK[h]);
    float sc = sqrtf(c);
    float invsc = __frcp_rn(sc);
    float a  = 0.125f * c * 1.4426950408889634f;
    float tmul = (z == 0) ? a : 1.0f;
    float vmul = (z == 0) ? -a : 1.0f;
    float* Tt = (z == 0) ? Qt : Kt;
    short* Ts = (z == 0) ? Qs : Ks;
    #pragma unroll
    for (int mi = 0; mi < 4; ++mi)
      #pragma unroll
      for (int r = 0; r < 4; ++r){
        float prt = 0.f;
        #pragma unroll
        for (int ni = 0; ni < 4; ++ni) prt += acc[mi][ni][r] * acc[mi][ni][r];
        prt += __shfl_xor(prt, 1);
        prt += __shfl_xor(prt, 2);
        prt += __shfl_xor(prt, 4);
        prt += __shfl_xor(prt, 8);
        float n = fmaxf(sqrtf(prt), 1e-7f);
        float arg = sc * n;
        float e = __expf(arg), ei = __frcp_rn(e);
        float tval = tmul * 0.5f * (e + ei) * invsc;
        float vscl = vmul * 0.5f * (e - ei) * __frcp_rn(arg);
        int grow = m0 + wm * 64 + mi * 16 + 4 * lg + r;
        int b = grow >> 11, s = grow & (S_LEN - 1);
        size_t bhs = ((size_t)(b * NH + h) * S_LEN + s);
        if (lr == 0) Tt[bhs] = tval;
        #pragma unroll
        for (int ni = 0; ni < 4; ++ni)
          Ts[bhs * DH + ni * 16 + lr] = f2bf(vscl * acc[mi][ni][r]);
      }
  } else {
    __syncthreads();                 // all waves done reading Stage
    short* vt = &Stage[0][0] + w * 4352;   // per-wave 64x68
    #pragma unroll
    for (int mi = 0; mi < 4; ++mi)
      #pragma unroll
      for (int ni = 0; ni < 4; ++ni)
        #pragma unroll
        for (int r = 0; r < 4; ++r)
          vt[(ni * 16 + lr) * 68 + mi * 16 + 4 * lg + r] = f2bf(acc[mi][ni][r]);
    int b = m0 >> 11;
    int sglob = (m0 & (S_LEN - 1)) + wm * 64;
    size_t vbase = ((size_t)(b * NH + h) * DH + lane) * S_LEN + sglob;
    #pragma unroll
    for (int j = 0; j < 8; ++j){
      s16x8 val = *(const s16x8*)&vt[lane * 68 + j * 8];
      *(s16x8*)(Vt + vbase + j * 8) = val;
    }
  }
}

// ---- K4: flash attention, uniform 256-key chunks (1152 blocks x 4 waves),
//      2-buffer / 2-barrier ring, 33 KB LDS -> 4 blocks/CU. nch==1 writes Obf. ----
__global__ __launch_bounds__(256, 4) void attn_kernel(const short* __restrict__ Qs,
                                                      const float* __restrict__ Qt,
                                                      const short* __restrict__ Ks,
                                                      const float* __restrict__ Kt,
                                                      const short* __restrict__ Vt,
                                                      float* __restrict__ Mpart,
                                                      float* __restrict__ Lpart,
                                                      short* __restrict__ Obn,
                                                      short* __restrict__ Obf){
  __shared__ __attribute__((aligned(16))) short Ksm[2][4096];
  __shared__ __attribute__((aligned(16))) short Vsm[2][4096];
  __shared__ __attribute__((aligned(16))) float Ktm[2][64];

  int bx = blockIdx.x;
  int bh = bx & 15;                  // XCD-local heads
  int id = bx >> 4;                  // 0..71 = S(g)+c, S(g)=floor((g+1)^2/4)
  int g = (int)(2.0f * __fsqrt_rn((float)(id + 1))) - 1;
  if (g < 0) g = 0;
  while (((g + 2) * (g + 2)) / 4 <= id) ++g;
  while (((g + 1) * (g + 1)) / 4 > id) --g;
  int c = id - ((g + 1) * (g + 1)) / 4;
  int nch = (g + 2) >> 1;
  int kbeg = 256 * c;
  int kend = 256 * c + 256; { int ge = 128 * (g + 1); if (ge < kend) kend = ge; }
  int ntc = (kend - kbeg) >> 6;      // 2 or 4

  int tid = threadIdx.x;
  int w = tid >> 6, lane = tid & 63;
  int l5 = lane & 31, hi = lane >> 5;
  size_t bhS = (size_t)bh * S_LEN;

  const short* Kg  = Ks + bhS * DH;
  const short* Vg  = Vt + (size_t)bh * DH * S_LEN;
  const float* Ktg = Kt + bhS;

  int srow = lane >> 3;
  int scol = ((lane & 7) * 8) ^ (srow << 3);
  const short* kg0 = Kg + (size_t)(kbeg + 16 * w + srow) * DH + scol;
  const short* kg1 = kg0 + 8 * DH;
  const short* vg0 = Vg + (size_t)(16 * w + srow) * S_LEN + kbeg + scol;
  const short* vg1 = vg0 + 8 * S_LEN;
  const float* ktg = Ktg + kbeg + lane;

  int q0w = 128 * g + 32 * w;
  int q   = q0w + l5;
  s16x8 qf[4];
  #pragma unroll
  for (int dblk = 0; dblk < 4; ++dblk)
    qf[dblk] = *(const s16x8*)(Qs + (bhS + q) * DH + dblk * 16 + hi * 8);
  float aqt = Qt[bhS + q];

  fx16 acc0, acc1;
  #pragma unroll
  for (int i = 0; i < 16; ++i){ acc0[i] = 0.f; acc1[i] = 0.f; }
  float mrun = 0.f, lrun = 0.f;

  #define STAGE_T(tt, b) { int off_ = (tt) * 64; \
    GLL16(kg0 + (size_t)off_ * DH, &Ksm[b][16 * w * 64]); \
    GLL16(kg1 + (size_t)off_ * DH, &Ksm[b][16 * w * 64 + 512]); \
    GLL16(vg0 + off_, &Vsm[b][16 * w * 64]); \
    GLL16(vg1 + off_, &Vsm[b][16 * w * 64 + 512]); \
    if (w == 3) GLL4(ktg + off_, &Ktm[b][0]); }

  STAGE_T(0, 0);
  if (ntc > 1) STAGE_T(1, 1);

  for (int t = 0; t < ntc; ++t){
    int k0 = kbeg + t * 64;
    if (t + 1 < ntc){
      if (w == 3) asm volatile("s_waitcnt vmcnt(5)" ::: "memory");
      else        asm volatile("s_waitcnt vmcnt(4)" ::: "memory");
    } else {
      asm volatile("s_waitcnt vmcnt(0)" ::: "memory");
    }
    __builtin_amdgcn_s_barrier();
    int buf = t & 1;

    {
      fx16 st[2];
      __builtin_amdgcn_s_setprio(1);
      #pragma unroll
      for (int s = 0; s < 2; ++s){
        const short* kb = &Ksm[buf][(32 * s + l5) * 64];
        fx16 z;
        #pragma unroll
        for (int i = 0; i < 16; ++i) z[i] = 0.f;
        #pragma unroll
        for (int dblk = 0; dblk < 4; ++dblk){
          s16x8 kf = *(const s16x8*)(kb + ((16 * dblk + 8 * hi) ^ ((l5 & 7) << 3)));
          z = mfma32(kf, qf[dblk], z);
        }
        st[s] = z;
      }
      __builtin_amdgcn_s_setprio(0);
      float p[2][16];
      #pragma unroll
      for (int s = 0; s < 2; ++s)
        #pragma unroll
        for (int m4 = 0; m4 < 4; ++m4){
          fx4 kt4 = *(const fx4*)&Ktm[buf][32 * s + 8 * m4 + 4 * hi];
          #pragma unroll
          for (int tt = 0; tt < 4; ++tt)
            p[s][4 * m4 + tt] = st[s][4 * m4 + tt] + aqt * kt4[tt];
        }
      if (k0 + 63 > q0w){
        #pragma unroll
        for (int s = 0; s < 2; ++s)
          #pragma unroll
          for (int r = 0; r < 16; ++r){
            int kg2 = k0 + 32 * s + (r & 3) + 8 * (r >> 2) + 4 * hi;
            if (kg2 > q) p[s][r] = -3e38f;
          }
      }
      float v16[16];
      #pragma unroll
      for (int i = 0; i < 16; ++i) v16[i] = fmaxf(p[0][i], p[1][i]);
      #pragma unroll
      for (int i = 0; i < 8; ++i) v16[i] = fmaxf(v16[i], v16[i + 8]);
      #pragma unroll
      for (int i = 0; i < 4; ++i) v16[i] = fmaxf(v16[i], v16[i + 4]);
      float pmax = fmaxf(fmaxf(v16[0], v16[1]), fmaxf(v16[2], v16[3]));
      pmax = fmaxf(pmax, __shfl_xor(pmax, 32));
      if (!__all(pmax <= mrun + 8.f)){
        float mnew = fmaxf(mrun, pmax);
        float scl = __builtin_amdgcn_exp2f(mrun - mnew);
        mrun = mnew;
        lrun *= scl;
        #pragma unroll
        for (int i = 0; i < 16; ++i){ acc0[i] *= scl; acc1[i] *= scl; }
      }
      float sm[16];
      #pragma unroll
      for (int i = 0; i < 16; ++i){
        p[0][i] = __builtin_amdgcn_exp2f(p[0][i] - mrun);
        p[1][i] = __builtin_amdgcn_exp2f(p[1][i] - mrun);
        sm[i] = p[0][i] + p[1][i];
      }
      #pragma unroll
      for (int i = 0; i < 8; ++i) sm[i] += sm[i + 8];
      #pragma unroll
      for (int i = 0; i < 4; ++i) sm[i] += sm[i + 4];
      float rsum = (sm[0] + sm[1]) + (sm[2] + sm[3]);
      rsum += __shfl_xor(rsum, 32);
      lrun += rsum;

      #pragma unroll
      for (int h2 = 0; h2 < 4; ++h2){
        int s = h2 >> 1, hb = h2 & 1;
        int w0 = cvtpk(p[s][8 * hb + 0], p[s][8 * hb + 1]);
        int w1 = cvtpk(p[s][8 * hb + 2], p[s][8 * hb + 3]);
        int w2 = cvtpk(p[s][8 * hb + 4], p[s][8 * hb + 5]);
        int w3 = cvtpk(p[s][8 * hb + 6], p[s][8 * hb + 7]);
        int sdA = hi ? w0 : w2;
        int sdB = hi ? w1 : w3;
        int rcA = __shfl_xor(sdA, 32);
        int rcB = __shfl_xor(sdB, 32);
        ix4 fw;
        fw.x = hi ? rcA : w0; fw.y = hi ? rcB : w1;
        fw.z = hi ? w2 : rcA; fw.w = hi ? w3 : rcB;
        s16x8 pf = __builtin_bit_cast(s16x8, fw);
        const short* vb0 = &Vsm[buf][(l5) * 64 + ((16 * h2 + 8 * hi) ^ ((l5 & 7) << 3))];
        const short* vb1 = vb0 + 32 * 64;
        s16x8 vf0 = *(const s16x8*)vb0;
        s16x8 vf1 = *(const s16x8*)vb1;
        __builtin_amdgcn_s_setprio(1);
        acc0 = mfma32(vf0, pf, acc0);
        acc1 = mfma32(vf1, pf, acc1);
        __builtin_amdgcn_s_setprio(0);
      }
    }
    __builtin_amdgcn_s_barrier();
    if (t + 2 < ntc) STAGE_T(t + 2, buf);
  }
  #undef STAGE_T

  // ---- epilogue: normalized output (acc/l), bf16 ----
  float invl = 1.0f / lrun;
  int qi = 32 * w + l5;
  if (nch == 1){
    int bb = bh >> 3, hh = bh & 7;
    short* orow = Obf + ((size_t)bb * S_LEN + 128 * g + qi) * DM + hh * DH;
    #pragma unroll
    for (int j = 0; j < 4; ++j){
      ix2 v0, v1;
      v0.x = cvtpk(acc0[4 * j + 0] * invl, acc0[4 * j + 1] * invl);
      v0.y = cvtpk(acc0[4 * j + 2] * invl, acc0[4 * j + 3] * invl);
      v1.x = cvtpk(acc1[4 * j + 0] * invl, acc1[4 * j + 1] * invl);
      v1.y = cvtpk(acc1[4 * j + 2] * invl, acc1[4 * j + 3] * invl);
      *(ix2*)(orow + 8 * j + 4 * hi)      = v0;
      *(ix2*)(orow + 32 + 8 * j + 4 * hi) = v1;
    }
  } else {
    int slot = bh * 72 + id;
    if (hi == 0){
      Mpart[(size_t)slot * 128 + qi] = mrun;
      Lpart[(size_t)slot * 128 + qi] = lrun;
    }
    short* Op = Obn + (size_t)slot * 8192 + (size_t)qi * 64;
    #pragma unroll
    for (int j = 0; j < 4; ++j){
      ix2 v0, v1;
      v0.x = cvtpk(acc0[4 * j + 0] * invl, acc0[4 * j + 1] * invl);
      v0.y = cvtpk(acc0[4 * j + 2] * invl, acc0[4 * j + 3] * invl);
      v1.x = cvtpk(acc1[4 * j + 0] * invl, acc1[4 * j + 1] * invl);
      v1.y = cvtpk(acc1[4 * j + 2] * invl, acc1[4 * j + 3] * invl);
      *(ix2*)(Op + 8 * j + 4 * hi)      = v0;
      *(ix2*)(Op + 32 + 8 * j + 4 * hi) = v1;
    }
  }
}

// ---- K4b: online-merge combine (g>=2), 896 blocks ----
__global__ __launch_bounds__(256) void combine_kernel(const float* __restrict__ Mpart,
                                                      const float* __restrict__ Lpart,
                                                      const short* __restrict__ Obn,
                                                      short* __restrict__ Obf){
  int bx = blockIdx.x;
  int bhg = bx % 224;
  int qq = bx / 224;                 // 0..3
  int bh = bhg & 15;
  int g = 2 + (bhg >> 4);            // 2..15
  int t = threadIdx.x;
  int q = qq * 32 + (t >> 3);
  int oct = t & 7;
  int nch = (g + 2) >> 1;
  int base = bh * 72 + ((g + 1) * (g + 1)) / 4;

  float Mr = -3e38f, Dr = 0.f;
  float acc[8] = {0.f,0.f,0.f,0.f,0.f,0.f,0.f,0.f};
  for (int c = 0; c < nch; ++c){
    float m = Mpart[(size_t)(base + c) * 128 + q];
    float l = Lpart[(size_t)(base + c) * 128 + q];
    float Mn = fmaxf(Mr, m);
    float sOld = __builtin_amdgcn_exp2f(Mr - Mn);
    float sNew = __builtin_amdgcn_exp2f(m - Mn) * l;
    s16x8 v = *(const s16x8*)(Obn + (size_t)(base + c) * 8192 + (size_t)q * 64 + oct * 8);
    #pragma unroll
    for (int i = 0; i < 8; ++i) acc[i] = acc[i] * sOld + sNew * bf2f(v[i]);
    Dr = Dr * sOld + sNew;
    Mr = Mn;
  }
  float invD = 1.f / Dr;
  s16x8 pk;
  #pragma unroll
  for (int dd = 0; dd < 8; ++dd) pk[dd] = f2bf(acc[dd] * invD);
  int bb = bh >> 3, hh = bh & 7;
  *(s16x8*)(Obf + ((size_t)bb * S_LEN + 128 * g + q) * DM + hh * DH + oct * 8) = pk;
}

// ---- K5: O-projection GEMM, 64x64 tiles, single-barrier loop ----
__global__ __launch_bounds__(256, 4) void gemm_o_kernel(const short* __restrict__ A,
                                                        const short* __restrict__ Bt,
                                                        float* __restrict__ C){
  __shared__ __attribute__((aligned(16))) short Asm[2][64 * 64];
  __shared__ __attribute__((aligned(16))) short Bsm[2][64 * 64];
  const int K = DM;
  int n0 = blockIdx.y * 64, m0 = blockIdx.x * 64;
  int t = threadIdx.x;
  int w = t >> 6, lane = t & 63;
  int wm = w >> 1, wn = w & 1;
  int lg = lane >> 4, lr = lane & 15;

  int aoff[2]; const short* asrcp[2];
  int boff[2]; const short* bsrcp[2];
  #pragma unroll
  for (int j = 0; j < 2; ++j){
    int ch = t + 256 * j;
    int r = ch >> 3, c = ch & 7;
    aoff[j] = ch * 8;
    asrcp[j] = A + (size_t)(m0 + r) * K + 8 * (c ^ (r & 7));
    boff[j] = ch * 8;
    bsrcp[j] = Bt + (size_t)(n0 + r) * K + 8 * (c ^ (r & 7));
  }

  {
    short* ab = &Asm[0][0]; short* bb = &Bsm[0][0];
    #pragma unroll
    for (int j = 0; j < 2; ++j){ GLL16(asrcp[j], ab + aoff[j]); GLL16(bsrcp[j], bb + boff[j]); }
  }

  fx4 acc[2][2] = {};
  for (int ks = 0; ks < 8; ++ks){
    asm volatile("s_waitcnt vmcnt(0)" ::: "memory");
    __builtin_amdgcn_s_barrier();
    if (ks < 7){
      int nb = (ks + 1) & 1;
      short* ab = &Asm[nb][0]; short* bb = &Bsm[nb][0];
      int kk = (ks + 1) * 64;
      #pragma unroll
      for (int j = 0; j < 2; ++j){ GLL16(asrcp[j] + kk, ab + aoff[j]); GLL16(bsrcp[j] + kk, bb + boff[j]); }
    }
    int buf = ks & 1;
    s16x8 af[2][2], bf[2][2];
    #pragma unroll
    for (int mi = 0; mi < 2; ++mi){
      int row = wm * 32 + mi * 16 + lr;
      #pragma unroll
      for (int s = 0; s < 2; ++s)
        af[mi][s] = *(const s16x8*)&Asm[buf][row * 64 + ((4 * s + lg) ^ (row & 7)) * 8];
    }
    #pragma unroll
    for (int ni = 0; ni < 2; ++ni){
      int row = wn * 32 + ni * 16 + lr;
      #pragma unroll
      for (int s = 0; s < 2; ++s)
        bf[ni][s] = *(const s16x8*)&Bsm[buf][row * 64 + ((4 * s + lg) ^ (row & 7)) * 8];
    }
    __builtin_amdgcn_s_setprio(1);
    #pragma unroll
    for (int s = 0; s < 2; ++s)
      #pragma unroll
      for (int mi = 0; mi < 2; ++mi)
        #pragma unroll
        for (int ni = 0; ni < 2; ++ni)
          acc[mi][ni] = mfma16(af[mi][s], bf[ni][s], acc[mi][ni]);
    __builtin_amdgcn_s_setprio(0);
  }

  #pragma unroll
  for (int mi = 0; mi < 2; ++mi)
    #pragma unroll
    for (int ni = 0; ni < 2; ++ni)
      #pragma unroll
      for (int r = 0; r < 4; ++r){
        int row = m0 + wm * 32 + mi * 16 + 4 * lg + r;
        int col = n0 + wn * 32 + ni * 16 + lr;
        C[(size_t)row * DM + col] = acc[mi][ni][r];
      }
}

extern "C" void kernel_launch(void* const* d_in, const int* in_sizes, int n_in,
                              void* d_out, int out_size, void* d_ws, size_t ws_size,
                              hipStream_t stream) {
  const float* x     = (const float*)d_in[0];
  const float* Wq    = (const float*)d_in[1];
  const float* Wk    = (const float*)d_in[2];
  const float* Wv    = (const float*)d_in[3];
  const float* Wo    = (const float*)d_in[4];
  const float* labsK = (const float*)d_in[5];

  char* w = (char*)d_ws;
  short* Wt    = (short*)(w);                                  // 2 MB
  short* xeu   = (short*)(w + (2ull  << 20));                  // 4 MB
  short* Qs    = (short*)(w + (30ull << 20));                  // 4 MB
  short* Ks    = (short*)(w + (34ull << 20));                  // 4 MB
  short* Vt    = (short*)(w + (38ull << 20));                  // 4 MB
  float* Qt    = (float*)(w + (42ull << 20));                  // 128 KB
  float* Kt    = (float*)(w + (42ull << 20) + (128ull << 10)); // 128 KB
  short* Obf   = (short*)(w + (42ull << 20) + (256ull << 10)); // 4 MB
  short* Obn   = (short*)(w + (48ull << 20));                  // ~19 MB (bf16 partials)
  float* Mpart = (float*)(w + (80ull << 20));                  // 590 KB
  float* Lpart = (float*)(w + (81ull << 20));                  // 590 KB

  prep_kernel<<<dim3(1280), 256, 0, stream>>>(Wq, Wk, Wv, Wo, Wt, x, xeu);

  gemm_fused_kernel<<<dim3(32, 4, 3), 256, 0, stream>>>(
      xeu, Wt, labsK, Qt, Qs, Kt, Ks, Vt);

  attn_kernel<<<dim3(1152), 256, 0, stream>>>(
      Qs, Qt, Ks, Kt, Vt, Mpart, Lpart, Obn, Obf);

  combine_kernel<<<dim3(896), 256, 0, stream>>>(Mpart, Lpart, Obn, Obf);

  gemm_o_kernel<<<dim3(64, 8), 256, 0, stream>>>(Obf, Wt + 3 * DM * DM, (float*)d_out);
}

// Round 14
// 59.209 us; speedup vs baseline: 1.3987x; 1.0236x over previous
//
#include <hip/hip_runtime.h>
#include <math.h>

#define S_LEN 2048
#define B_SZ 2
#define NH 8
#define DH 64
#define DM 512
#define MROWS 4096  // B*S

typedef __attribute__((ext_vector_type(8))) short s16x8;
typedef __attribute__((ext_vector_type(4))) float fx4;
typedef __attribute__((ext_vector_type(16))) float fx16;
typedef __attribute__((ext_vector_type(4))) int ix4;
typedef __attribute__((ext_vector_type(2))) int ix2;

__device__ inline short f2bf(float x){
  unsigned u = __float_as_uint(x);
  u = (u + 0x7FFFu + ((u >> 16) & 1u)) >> 16;
  return (short)u;
}

__device__ inline fx4 mfma16(s16x8 a, s16x8 b, fx4 c){
  return __builtin_amdgcn_mfma_f32_16x16x32_bf16(a, b, c, 0, 0, 0);
}
__device__ inline fx16 mfma32(s16x8 a, s16x8 b, fx16 c){
  return __builtin_amdgcn_mfma_f32_32x32x16_bf16(a, b, c, 0, 0, 0);
}
__device__ inline int cvtpk(float a, float b){
  int r; asm("v_cvt_pk_bf16_f32 %0, %1, %2" : "=v"(r) : "v"(a), "v"(b)); return r;
}

#define GLL16(g, l) __builtin_amdgcn_global_load_lds((const __attribute__((address_space(1))) void*)(g), (__attribute__((address_space(3))) void*)(l), 16, 0, 0)
#define GLL4(g, l)  __builtin_amdgcn_global_load_lds((const __attribute__((address_space(1))) void*)(g), (__attribute__((address_space(3))) void*)(l), 4, 0, 0)

// ---- K0: fused weight-transpose (blocks 0..255) + logmap (blocks 256..1279) ----
__global__ __launch_bounds__(256) void prep_kernel(const float* __restrict__ W0,
                                                   const float* __restrict__ W1,
                                                   const float* __restrict__ W2,
                                                   const float* __restrict__ W3,
                                                   short* __restrict__ Wt,
                                                   const float* __restrict__ x,
                                                   short* __restrict__ xeu){
  __shared__ short tile[64][66];
  int bid = blockIdx.x;
  int t = threadIdx.x;
  if (bid < 256){
    int z = bid >> 6, rem = bid & 63;
    const float* W = (z == 0) ? W0 : (z == 1) ? W1 : (z == 2) ? W2 : W3;
    short* Wtz = Wt + (size_t)z * DM * DM;
    int n0 = (rem & 7) * 64, k0 = (rem >> 3) * 64;
    int nl = t & 63;
    #pragma unroll
    for (int p = 0; p < 16; ++p){
      int kl = (t >> 6) + p * 4;
      tile[kl][nl] = f2bf(W[(size_t)(k0 + kl) * DM + n0 + nl]);
    }
    __syncthreads();
    int kl2 = t & 63;
    #pragma unroll
    for (int p = 0; p < 16; ++p){
      int nl2 = (t >> 6) + p * 4;
      Wtz[(size_t)(n0 + nl2) * DM + k0 + kl2] = tile[kl2][nl2];
    }
  } else {
    int row = (bid - 256) * 4 + (t >> 6);
    int lane = t & 63;
    const float* xr = x + (size_t)row * (DM + 1);
    float v[8]; float ss = 0.f;
    #pragma unroll
    for (int j = 0; j < 8; ++j){
      v[j] = xr[1 + lane * 8 + j];
      ss += v[j] * v[j];
    }
    #pragma unroll
    for (int off = 1; off < 64; off <<= 1) ss += __shfl_xor(ss, off);
    float nrm = sqrtf(ss);
    float theta = acoshf(fmaxf(xr[0], 1.0f + 1e-7f));
    float scl = theta / fmaxf(nrm, 1e-7f);
    s16x8 pk;
    #pragma unroll
    for (int j = 0; j < 8; ++j) pk[j] = f2bf(scl * v[j]);
    *(s16x8*)(xeu + (size_t)row * DM + lane * 8) = pk;
  }
}

// ---- K2: QKV GEMM 128x128 tiles (wave = one head) + fused exp-map / V-transpose ----
__global__ __launch_bounds__(256, 2) void gemm_fused_kernel(const short* __restrict__ A,
                                                            const short* __restrict__ Bt,
                                                            const float* __restrict__ labsK,
                                                            float* __restrict__ Qt,
                                                            short* __restrict__ Qs,
                                                            float* __restrict__ Kt,
                                                            short* __restrict__ Ks,
                                                            short* __restrict__ Vt){
  __shared__ __attribute__((aligned(16))) short Stage[4][8192]; // [0..1]=A, [2..3]=B
  const int K = DM;
  int z = blockIdx.z;
  int hp = blockIdx.y;                // head pair
  int n0 = hp * 128, m0 = blockIdx.x * 128;
  int t = threadIdx.x;
  int w = t >> 6, lane = t & 63;
  int wm = w >> 1, wn = w & 1;
  int lg = lane >> 4, lr = lane & 15;
  const short* Btz = Bt + (size_t)z * K * DM;

  int coff[4]; const short* asrcp[4]; const short* bsrcp[4];
  #pragma unroll
  for (int j = 0; j < 4; ++j){
    int ch = t + 256 * j;
    int r = ch >> 3, c = ch & 7;
    coff[j] = ch * 8;
    asrcp[j] = A   + (size_t)(m0 + r) * K + 8 * (c ^ (r & 7));
    bsrcp[j] = Btz + (size_t)(n0 + r) * K + 8 * (c ^ (r & 7));
  }

  #pragma unroll
  for (int j = 0; j < 4; ++j){
    GLL16(asrcp[j], &Stage[0][coff[j]]);
    GLL16(bsrcp[j], &Stage[2][coff[j]]);
  }

  fx4 acc[4][4] = {};
  for (int ks = 0; ks < 8; ++ks){
    asm volatile("s_waitcnt vmcnt(0)" ::: "memory");
    __builtin_amdgcn_s_barrier();
    if (ks < 7){
      int nb = (ks + 1) & 1;
      int kk = (ks + 1) * 64;
      #pragma unroll
      for (int j = 0; j < 4; ++j){
        GLL16(asrcp[j] + kk, &Stage[nb][coff[j]]);
        GLL16(bsrcp[j] + kk, &Stage[2 + nb][coff[j]]);
      }
    }
    int buf = ks & 1;
    s16x8 af[4][2], bf[4][2];
    #pragma unroll
    for (int mi = 0; mi < 4; ++mi){
      int row = wm * 64 + mi * 16 + lr;
      #pragma unroll
      for (int s = 0; s < 2; ++s)
        af[mi][s] = *(const s16x8*)&Stage[buf][row * 64 + ((4 * s + lg) ^ (row & 7)) * 8];
    }
    #pragma unroll
    for (int ni = 0; ni < 4; ++ni){
      int row = wn * 64 + ni * 16 + lr;
      #pragma unroll
      for (int s = 0; s < 2; ++s)
        bf[ni][s] = *(const s16x8*)&Stage[2 + buf][row * 64 + ((4 * s + lg) ^ (row & 7)) * 8];
    }
    __builtin_amdgcn_s_setprio(1);
    #pragma unroll
    for (int s = 0; s < 2; ++s)
      #pragma unroll
      for (int mi = 0; mi < 4; ++mi)
        #pragma unroll
        for (int ni = 0; ni < 4; ++ni)
          acc[mi][ni] = mfma16(af[mi][s], bf[ni][s], acc[mi][ni]);
    __builtin_amdgcn_s_setprio(0);
  }

  int h = hp * 2 + wn;                // this wave's head
  if (z < 2){
    float c  = __expf(labsK[h]);
    float sc = sqrtf(c);
    float invsc = __frcp_rn(sc);
    float a  = 0.125f * c * 1.4426950408889634f;
    float tmul = (z == 0) ? a : 1.0f;
    float vmul = (z == 0) ? -a : 1.0f;
    float* Tt = (z == 0) ? Qt : Kt;
    short* Ts = (z == 0) ? Qs : Ks;
    #pragma unroll
    for (int mi = 0; mi < 4; ++mi)
      #pragma unroll
      for (int r = 0; r < 4; ++r){
        float prt = 0.f;
        #pragma unroll
        for (int ni = 0; ni < 4; ++ni) prt += acc[mi][ni][r] * acc[mi][ni][r];
        prt += __shfl_xor(prt, 1);
        prt += __shfl_xor(prt, 2);
        prt += __shfl_xor(prt, 4);
        prt += __shfl_xor(prt, 8);
        float n = fmaxf(sqrtf(prt), 1e-7f);
        float arg = sc * n;
        float e = __expf(arg), ei = __frcp_rn(e);
        float tval = tmul * 0.5f * (e + ei) * invsc;
        float vscl = vmul * 0.5f * (e - ei) * __frcp_rn(arg);
        int grow = m0 + wm * 64 + mi * 16 + 4 * lg + r;
        int b = grow >> 11, s = grow & (S_LEN - 1);
        size_t bhs = ((size_t)(b * NH + h) * S_LEN + s);
        if (lr == 0) Tt[bhs] = tval;
        #pragma unroll
        for (int ni = 0; ni < 4; ++ni)
          Ts[bhs * DH + ni * 16 + lr] = f2bf(vscl * acc[mi][ni][r]);
      }
  } else {
    __syncthreads();                 // all waves done reading Stage
    short* vt = &Stage[0][0] + w * 4352;   // per-wave 64x68
    #pragma unroll
    for (int mi = 0; mi < 4; ++mi)
      #pragma unroll
      for (int ni = 0; ni < 4; ++ni)
        #pragma unroll
        for (int r = 0; r < 4; ++r)
          vt[(ni * 16 + lr) * 68 + mi * 16 + 4 * lg + r] = f2bf(acc[mi][ni][r]);
    int b = m0 >> 11;
    int sglob = (m0 & (S_LEN - 1)) + wm * 64;
    size_t vbase = ((size_t)(b * NH + h) * DH + lane) * S_LEN + sglob;
    #pragma unroll
    for (int j = 0; j < 8; ++j){
      s16x8 val = *(const s16x8*)&vt[lane * 68 + j * 8];
      *(s16x8*)(Vt + vbase + j * 8) = val;
    }
  }
}

// ---- K4: flash attention, IN-BLOCK key-split. Block = (bh, 32-q group); 4 waves
// each walk strided 32-key tiles with private double-buffered LDS (no barriers in
// loop, per-wave counted vmcnt); end-of-block LDS merge writes Obf directly. ----
__global__ __launch_bounds__(256, 2) void attn_kernel(const short* __restrict__ Qs,
                                                      const float* __restrict__ Qt,
                                                      const short* __restrict__ Ks,
                                                      const float* __restrict__ Kt,
                                                      const short* __restrict__ Vt,
                                                      short* __restrict__ Obf){
  __shared__ __attribute__((aligned(16))) char SMEM[66560];  // 65 KB

  int bx = blockIdx.x;
  int bh = bx & 15;                  // XCD-local heads
  int qg = 63 - (bx >> 4);           // longest first
  int tid = threadIdx.x;
  int w = tid >> 6, lane = tid & 63;
  int l5 = lane & 31, hi = lane >> 5;
  int qB = qg * 32;
  int q  = qB + l5;
  size_t bhS = (size_t)bh * S_LEN;

  // per-wave arenas
  short* Kar  = (short*)(SMEM)          + w * 4096;   // [2][32 key][64 d]
  short* Var  = (short*)(SMEM + 32768)  + w * 4096;   // [2][64 d][32 s]
  float* Ktar = (float*)(SMEM + 65536)  + w * 64;     // [2][32]

  const short* Kg  = Ks + bhS * DH;
  const short* Vg  = Vt + (size_t)bh * DH * S_LEN;
  const float* KtG = Kt + bhS;

  int srowK = lane >> 3;                               // 0..7
  int scolK = ((lane & 7) * 8) ^ (srowK << 3);
  int drV   = lane >> 2;                               // 0..15
  int gsV   = ((lane & 3) * 8) ^ ((drV & 3) << 3);

  // Q fragments (B operand: col=q=l5, k(d)=8*hi+j) — same for all waves
  s16x8 qf[4];
  #pragma unroll
  for (int dblk = 0; dblk < 4; ++dblk)
    qf[dblk] = *(const s16x8*)(Qs + (bhS + q) * DH + dblk * 16 + hi * 8);
  float aqt = Qt[bhS + q];

  fx16 acc0, acc1;
  #pragma unroll
  for (int i = 0; i < 16; ++i){ acc0[i] = 0.f; acc1[i] = 0.f; }
  float mrun = 0.f, lrun = 0.f;

  int nt = qg + 1;                   // 32-key tiles 0..qg

  // 9 VMEM issues per tile (4 K + 4 V + 1 Kt)
  #define STG(kb_, b_) { \
    _Pragma("unroll") \
    for (int i_ = 0; i_ < 4; ++i_) \
      GLL16(Kg + (size_t)((kb_) + 8 * i_ + srowK) * DH + scolK, Kar + (b_) * 2048 + i_ * 512); \
    _Pragma("unroll") \
    for (int i_ = 0; i_ < 4; ++i_) \
      GLL16(Vg + (size_t)(16 * i_ + drV) * S_LEN + (kb_) + gsV, Var + (b_) * 2048 + i_ * 512); \
    if (lane < 32) GLL4(KtG + (kb_) + lane, Ktar + (b_) * 32); }

  if (w < nt)     STG(32 * w, 0);
  if (w + 4 < nt) STG(32 * (w + 4), 1);

  int pb = 0;
  for (int t = w; t < nt; t += 4){
    if (t + 4 < nt) asm volatile("s_waitcnt vmcnt(9)" ::: "memory");
    else            asm volatile("s_waitcnt vmcnt(0)" ::: "memory");
    int buf = pb;
    int kb = 32 * t;

    // ---- QK^T (swapped): S^T[32 k][32 q] ----
    fx16 st;
    #pragma unroll
    for (int i = 0; i < 16; ++i) st[i] = 0.f;
    __builtin_amdgcn_s_setprio(1);
    const short* kbp = Kar + buf * 2048;
    #pragma unroll
    for (int dblk = 0; dblk < 4; ++dblk){
      s16x8 kf = *(const s16x8*)(kbp + l5 * 64 + ((16 * dblk + 8 * hi) ^ ((l5 & 7) << 3)));
      st = mfma32(kf, qf[dblk], st);
    }
    __builtin_amdgcn_s_setprio(0);

    // ---- rank-1 Lorentz time term + causal mask (last tile only) ----
    float p[16];
    #pragma unroll
    for (int m4 = 0; m4 < 4; ++m4){
      fx4 kt4 = *(const fx4*)(Ktar + buf * 32 + 8 * m4 + 4 * hi);
      #pragma unroll
      for (int tt = 0; tt < 4; ++tt)
        p[4 * m4 + tt] = st[4 * m4 + tt] + aqt * kt4[tt];
    }
    if (t == qg){
      #pragma unroll
      for (int r = 0; r < 16; ++r){
        int kg2 = kb + (r & 3) + 8 * (r >> 2) + 4 * hi;
        if (kg2 > q) p[r] = -3e38f;
      }
    }

    // ---- online softmax (32 keys: 16 in-lane + partner via shfl 32) ----
    float v8[8];
    #pragma unroll
    for (int i = 0; i < 8; ++i) v8[i] = fmaxf(p[i], p[i + 8]);
    #pragma unroll
    for (int i = 0; i < 4; ++i) v8[i] = fmaxf(v8[i], v8[i + 4]);
    float pmax = fmaxf(fmaxf(v8[0], v8[1]), fmaxf(v8[2], v8[3]));
    pmax = fmaxf(pmax, __shfl_xor(pmax, 32));
    if (!__all(pmax <= mrun + 8.f)){
      float mnew = fmaxf(mrun, pmax);
      float scl = __builtin_amdgcn_exp2f(mrun - mnew);
      mrun = mnew;
      lrun *= scl;
      #pragma unroll
      for (int i = 0; i < 16; ++i){ acc0[i] *= scl; acc1[i] *= scl; }
    }
    float sm[8];
    #pragma unroll
    for (int i = 0; i < 8; ++i){
      p[i]     = __builtin_amdgcn_exp2f(p[i] - mrun);
      p[i + 8] = __builtin_amdgcn_exp2f(p[i + 8] - mrun);
      sm[i] = p[i] + p[i + 8];
    }
    #pragma unroll
    for (int i = 0; i < 4; ++i) sm[i] += sm[i + 4];
    float rsum = (sm[0] + sm[1]) + (sm[2] + sm[3]);
    rsum += __shfl_xor(rsum, 32);
    lrun += rsum;

    // ---- pack P to bf16 B-fragments + PV ----
    #pragma unroll
    for (int hb = 0; hb < 2; ++hb){
      int w0 = cvtpk(p[8 * hb + 0], p[8 * hb + 1]);
      int w1 = cvtpk(p[8 * hb + 2], p[8 * hb + 3]);
      int w2 = cvtpk(p[8 * hb + 4], p[8 * hb + 5]);
      int w3 = cvtpk(p[8 * hb + 6], p[8 * hb + 7]);
      int sdA = hi ? w0 : w2;
      int sdB = hi ? w1 : w3;
      int rcA = __shfl_xor(sdA, 32);
      int rcB = __shfl_xor(sdB, 32);
      ix4 fw;
      fw.x = hi ? rcA : w0; fw.y = hi ? rcB : w1;
      fw.z = hi ? w2 : rcA; fw.w = hi ? w3 : rcB;
      s16x8 pf = __builtin_bit_cast(s16x8, fw);
      const short* vb0 = Var + buf * 2048 + l5 * 32 + ((16 * hb + 8 * hi) ^ ((l5 & 3) << 3));
      const short* vb1 = vb0 + 32 * 32;
      s16x8 vf0 = *(const s16x8*)vb0;
      s16x8 vf1 = *(const s16x8*)vb1;
      __builtin_amdgcn_s_setprio(1);
      acc0 = mfma32(vf0, pf, acc0);
      acc1 = mfma32(vf1, pf, acc1);
      __builtin_amdgcn_s_setprio(0);
    }

    if (t + 8 < nt) STG(32 * (t + 8), buf);
    pb ^= 1;
  }
  #undef STG

  // ---- in-block merge of 4 wave-partials (weights e^{m_w - M} cancel M) ----
  float* Mw   = (float*)(SMEM);            // [4][32]
  float* Lw   = (float*)(SMEM + 512);      // [4][32]
  float* Oacc = (float*)(SMEM + 1024);     // [4][32][68]
  __syncthreads();                          // all waves done with K/V arenas
  if (hi == 0){ Mw[w * 32 + l5] = mrun; Lw[w * 32 + l5] = lrun; }
  __syncthreads();
  float M = fmaxf(fmaxf(Mw[l5], Mw[32 + l5]), fmaxf(Mw[64 + l5], Mw[96 + l5]));
  float D = __builtin_amdgcn_exp2f(Mw[l5]      - M) * Lw[l5]
          + __builtin_amdgcn_exp2f(Mw[32 + l5] - M) * Lw[32 + l5]
          + __builtin_amdgcn_exp2f(Mw[64 + l5] - M) * Lw[64 + l5]
          + __builtin_amdgcn_exp2f(Mw[96 + l5] - M) * Lw[96 + l5];
  float swt = __builtin_amdgcn_exp2f(mrun - M) / D;
  float* Or = Oacc + (w * 32 + l5) * 68;
  #pragma unroll
  for (int m4 = 0; m4 < 4; ++m4){
    fx4 v0, v1;
    #pragma unroll
    for (int i = 0; i < 4; ++i){ v0[i] = acc0[4 * m4 + i] * swt; v1[i] = acc1[4 * m4 + i] * swt; }
    *(fx4*)(Or + 8 * m4 + 4 * hi)      = v0;
    *(fx4*)(Or + 32 + 8 * m4 + 4 * hi) = v1;
  }
  __syncthreads();
  int qq2 = tid >> 3;            // 0..31
  int d0  = (tid & 7) * 8;
  float o[8];
  #pragma unroll
  for (int i = 0; i < 8; ++i)
    o[i] = Oacc[(qq2) * 68 + d0 + i] + Oacc[(32 + qq2) * 68 + d0 + i]
         + Oacc[(64 + qq2) * 68 + d0 + i] + Oacc[(96 + qq2) * 68 + d0 + i];
  ix4 pkw;
  pkw.x = cvtpk(o[0], o[1]); pkw.y = cvtpk(o[2], o[3]);
  pkw.z = cvtpk(o[4], o[5]); pkw.w = cvtpk(o[6], o[7]);
  int bb = bh >> 3, hh = bh & 7;
  *(ix4*)(Obf + ((size_t)bb * S_LEN + qB + qq2) * DM + hh * DH + d0) = pkw;
}

// ---- K5: O-projection GEMM, 64x64 tiles, single-barrier loop ----
__global__ __launch_bounds__(256, 4) void gemm_o_kernel(const short* __restrict__ A,
                                                        const short* __restrict__ Bt,
                                                        float* __restrict__ C){
  __shared__ __attribute__((aligned(16))) short Asm[2][64 * 64];
  __shared__ __attribute__((aligned(16))) short Bsm[2][64 * 64];
  const int K = DM;
  int n0 = blockIdx.y * 64, m0 = blockIdx.x * 64;
  int t = threadIdx.x;
  int w = t >> 6, lane = t & 63;
  int wm = w >> 1, wn = w & 1;
  int lg = lane >> 4, lr = lane & 15;

  int aoff[2]; const short* asrcp[2];
  int boff[2]; const short* bsrcp[2];
  #pragma unroll
  for (int j = 0; j < 2; ++j){
    int ch = t + 256 * j;
    int r = ch >> 3, c = ch & 7;
    aoff[j] = ch * 8;
    asrcp[j] = A + (size_t)(m0 + r) * K + 8 * (c ^ (r & 7));
    boff[j] = ch * 8;
    bsrcp[j] = Bt + (size_t)(n0 + r) * K + 8 * (c ^ (r & 7));
  }

  {
    short* ab = &Asm[0][0]; short* bb = &Bsm[0][0];
    #pragma unroll
    for (int j = 0; j < 2; ++j){ GLL16(asrcp[j], ab + aoff[j]); GLL16(bsrcp[j], bb + boff[j]); }
  }

  fx4 acc[2][2] = {};
  for (int ks = 0; ks < 8; ++ks){
    asm volatile("s_waitcnt vmcnt(0)" ::: "memory");
    __builtin_amdgcn_s_barrier();
    if (ks < 7){
      int nb = (ks + 1) & 1;
      short* ab = &Asm[nb][0]; short* bb = &Bsm[nb][0];
      int kk = (ks + 1) * 64;
      #pragma unroll
      for (int j = 0; j < 2; ++j){ GLL16(asrcp[j] + kk, ab + aoff[j]); GLL16(bsrcp[j] + kk, bb + boff[j]); }
    }
    int buf = ks & 1;
    s16x8 af[2][2], bf[2][2];
    #pragma unroll
    for (int mi = 0; mi < 2; ++mi){
      int row = wm * 32 + mi * 16 + lr;
      #pragma unroll
      for (int s = 0; s < 2; ++s)
        af[mi][s] = *(const s16x8*)&Asm[buf][row * 64 + ((4 * s + lg) ^ (row & 7)) * 8];
    }
    #pragma unroll
    for (int ni = 0; ni < 2; ++ni){
      int row = wn * 32 + ni * 16 + lr;
      #pragma unroll
      for (int s = 0; s < 2; ++s)
        bf[ni][s] = *(const s16x8*)&Bsm[buf][row * 64 + ((4 * s + lg) ^ (row & 7)) * 8];
    }
    __builtin_amdgcn_s_setprio(1);
    #pragma unroll
    for (int s = 0; s < 2; ++s)
      #pragma unroll
      for (int mi = 0; mi < 2; ++mi)
        #pragma unroll
        for (int ni = 0; ni < 2; ++ni)
          acc[mi][ni] = mfma16(af[mi][s], bf[ni][s], acc[mi][ni]);
    __builtin_amdgcn_s_setprio(0);
  }

  #pragma unroll
  for (int mi = 0; mi < 2; ++mi)
    #pragma unroll
    for (int ni = 0; ni < 2; ++ni)
      #pragma unroll
      for (int r = 0; r < 4; ++r){
        int row = m0 + wm * 32 + mi * 16 + 4 * lg + r;
        int col = n0 + wn * 32 + ni * 16 + lr;
        C[(size_t)row * DM + col] = acc[mi][ni][r];
      }
}

extern "C" void kernel_launch(void* const* d_in, const int* in_sizes, int n_in,
                              void* d_out, int out_size, void* d_ws, size_t ws_size,
                              hipStream_t stream) {
  const float* x     = (const float*)d_in[0];
  const float* Wq    = (const float*)d_in[1];
  const float* Wk    = (const float*)d_in[2];
  const float* Wv    = (const float*)d_in[3];
  const float* Wo    = (const float*)d_in[4];
  const float* labsK = (const float*)d_in[5];

  char* w = (char*)d_ws;
  short* Wt    = (short*)(w);                                  // 2 MB
  short* xeu   = (short*)(w + (2ull  << 20));                  // 4 MB
  short* Qs    = (short*)(w + (30ull << 20));                  // 4 MB
  short* Ks    = (short*)(w + (34ull << 20));                  // 4 MB
  short* Vt    = (short*)(w + (38ull << 20));                  // 4 MB
  float* Qt    = (float*)(w + (42ull << 20));                  // 128 KB
  float* Kt    = (float*)(w + (42ull << 20) + (128ull << 10)); // 128 KB
  short* Obf   = (short*)(w + (42ull << 20) + (256ull << 10)); // 4 MB

  prep_kernel<<<dim3(1280), 256, 0, stream>>>(Wq, Wk, Wv, Wo, Wt, x, xeu);

  gemm_fused_kernel<<<dim3(32, 4, 3), 256, 0, stream>>>(
      xeu, Wt, labsK, Qt, Qs, Kt, Ks, Vt);

  attn_kernel<<<dim3(1024), 256, 0, stream>>>(Qs, Qt, Ks, Kt, Vt, Obf);

  gemm_o_kernel<<<dim3(64, 8), 256, 0, stream>>>(Obf, Wt + 3 * DM * DM, (float*)d_out);
}

// Round 15
// 59.086 us; speedup vs baseline: 1.4016x; 1.0021x over previous
//
#include <hip/hip_runtime.h>
#include <math.h>

#define S_LEN 2048
#define B_SZ 2
#define NH 8
#define DH 64
#define DM 512
#define MROWS 4096  // B*S

typedef __attribute__((ext_vector_type(8))) short s16x8;
typedef __attribute__((ext_vector_type(4))) float fx4;
typedef __attribute__((ext_vector_type(16))) float fx16;
typedef __attribute__((ext_vector_type(4))) int ix4;
typedef __attribute__((ext_vector_type(2))) int ix2;

__device__ inline short f2bf(float x){
  unsigned u = __float_as_uint(x);
  u = (u + 0x7FFFu + ((u >> 16) & 1u)) >> 16;
  return (short)u;
}

__device__ inline fx4 mfma16(s16x8 a, s16x8 b, fx4 c){
  return __builtin_amdgcn_mfma_f32_16x16x32_bf16(a, b, c, 0, 0, 0);
}
__device__ inline fx16 mfma32(s16x8 a, s16x8 b, fx16 c){
  return __builtin_amdgcn_mfma_f32_32x32x16_bf16(a, b, c, 0, 0, 0);
}
__device__ inline int cvtpk(float a, float b){
  int r; asm("v_cvt_pk_bf16_f32 %0, %1, %2" : "=v"(r) : "v"(a), "v"(b)); return r;
}

#define GLL16(g, l) __builtin_amdgcn_global_load_lds((const __attribute__((address_space(1))) void*)(g), (__attribute__((address_space(3))) void*)(l), 16, 0, 0)
#define GLL4(g, l)  __builtin_amdgcn_global_load_lds((const __attribute__((address_space(1))) void*)(g), (__attribute__((address_space(3))) void*)(l), 4, 0, 0)

// ---- K0: fused weight-transpose (blocks 0..255) + logmap (blocks 256..511) ----
// logmap uses the hyperboloid identity: ||x_s|| = sqrt(x_t^2 - 1)  ->  elementwise.
__global__ __launch_bounds__(256) void prep_kernel(const float* __restrict__ W0,
                                                   const float* __restrict__ W1,
                                                   const float* __restrict__ W2,
                                                   const float* __restrict__ W3,
                                                   short* __restrict__ Wt,
                                                   const float* __restrict__ x,
                                                   short* __restrict__ xeu){
  __shared__ short tile[64][66];
  int bid = blockIdx.x;
  int t = threadIdx.x;
  if (bid < 256){
    int z = bid >> 6, rem = bid & 63;
    const float* W = (z == 0) ? W0 : (z == 1) ? W1 : (z == 2) ? W2 : W3;
    short* Wtz = Wt + (size_t)z * DM * DM;
    int n0 = (rem & 7) * 64, k0 = (rem >> 3) * 64;
    int nl = t & 63;
    #pragma unroll
    for (int p = 0; p < 16; ++p){
      int kl = (t >> 6) + p * 4;
      tile[kl][nl] = f2bf(W[(size_t)(k0 + kl) * DM + n0 + nl]);
    }
    __syncthreads();
    int kl2 = t & 63;
    #pragma unroll
    for (int p = 0; p < 16; ++p){
      int nl2 = (t >> 6) + p * 4;
      Wtz[(size_t)(n0 + nl2) * DM + k0 + kl2] = tile[kl2][nl2];
    }
  } else {
    int lane = t & 63;
    int base_row = (bid - 256) * 16 + (t >> 6) * 4;   // 4 rows per wave
    #pragma unroll
    for (int rr = 0; rr < 4; ++rr){
      int row = base_row + rr;
      const float* xr = x + (size_t)row * (DM + 1);
      float xt = fmaxf(xr[0], 1.0f + 1e-7f);
      float nrm = fmaxf(__fsqrt_rn(xt * xt - 1.0f), 1e-7f);
      float scl = acoshf(xt) / nrm;
      fx4 a = *(const fx4*)(xr + 1 + lane * 8);
      fx4 b = *(const fx4*)(xr + 1 + lane * 8 + 4);
      s16x8 pk;
      #pragma unroll
      for (int j = 0; j < 4; ++j){ pk[j] = f2bf(scl * a[j]); pk[4 + j] = f2bf(scl * b[j]); }
      *(s16x8*)(xeu + (size_t)row * DM + lane * 8) = pk;
    }
  }
}

// ---- K2: QKV GEMM 128x128 tiles (wave = one head) + fused exp-map / V-transpose ----
__global__ __launch_bounds__(256, 2) void gemm_fused_kernel(const short* __restrict__ A,
                                                            const short* __restrict__ Bt,
                                                            const float* __restrict__ labsK,
                                                            float* __restrict__ Qt,
                                                            short* __restrict__ Qs,
                                                            float* __restrict__ Kt,
                                                            short* __restrict__ Ks,
                                                            short* __restrict__ Vt){
  __shared__ __attribute__((aligned(16))) short Stage[4][8192]; // [0..1]=A, [2..3]=B
  const int K = DM;
  int z = blockIdx.z;
  int hp = blockIdx.y;                // head pair
  int n0 = hp * 128, m0 = blockIdx.x * 128;
  int t = threadIdx.x;
  int w = t >> 6, lane = t & 63;
  int wm = w >> 1, wn = w & 1;
  int lg = lane >> 4, lr = lane & 15;
  const short* Btz = Bt + (size_t)z * K * DM;

  int coff[4]; const short* asrcp[4]; const short* bsrcp[4];
  #pragma unroll
  for (int j = 0; j < 4; ++j){
    int ch = t + 256 * j;
    int r = ch >> 3, c = ch & 7;
    coff[j] = ch * 8;
    asrcp[j] = A   + (size_t)(m0 + r) * K + 8 * (c ^ (r & 7));
    bsrcp[j] = Btz + (size_t)(n0 + r) * K + 8 * (c ^ (r & 7));
  }

  #pragma unroll
  for (int j = 0; j < 4; ++j){
    GLL16(asrcp[j], &Stage[0][coff[j]]);
    GLL16(bsrcp[j], &Stage[2][coff[j]]);
  }

  fx4 acc[4][4] = {};
  for (int ks = 0; ks < 8; ++ks){
    asm volatile("s_waitcnt vmcnt(0)" ::: "memory");
    __builtin_amdgcn_s_barrier();
    if (ks < 7){
      int nb = (ks + 1) & 1;
      int kk = (ks + 1) * 64;
      #pragma unroll
      for (int j = 0; j < 4; ++j){
        GLL16(asrcp[j] + kk, &Stage[nb][coff[j]]);
        GLL16(bsrcp[j] + kk, &Stage[2 + nb][coff[j]]);
      }
    }
    int buf = ks & 1;
    s16x8 af[4][2], bf[4][2];
    #pragma unroll
    for (int mi = 0; mi < 4; ++mi){
      int row = wm * 64 + mi * 16 + lr;
      #pragma unroll
      for (int s = 0; s < 2; ++s)
        af[mi][s] = *(const s16x8*)&Stage[buf][row * 64 + ((4 * s + lg) ^ (row & 7)) * 8];
    }
    #pragma unroll
    for (int ni = 0; ni < 4; ++ni){
      int row = wn * 64 + ni * 16 + lr;
      #pragma unroll
      for (int s = 0; s < 2; ++s)
        bf[ni][s] = *(const s16x8*)&Stage[2 + buf][row * 64 + ((4 * s + lg) ^ (row & 7)) * 8];
    }
    __builtin_amdgcn_s_setprio(1);
    #pragma unroll
    for (int s = 0; s < 2; ++s)
      #pragma unroll
      for (int mi = 0; mi < 4; ++mi)
        #pragma unroll
        for (int ni = 0; ni < 4; ++ni)
          acc[mi][ni] = mfma16(af[mi][s], bf[ni][s], acc[mi][ni]);
    __builtin_amdgcn_s_setprio(0);
  }

  int h = hp * 2 + wn;                // this wave's head
  if (z < 2){
    float c  = __expf(labsK[h]);
    float sc = sqrtf(c);
    float invsc = __frcp_rn(sc);
    float a  = 0.125f * c * 1.4426950408889634f;
    float tmul = (z == 0) ? a : 1.0f;
    float vmul = (z == 0) ? -a : 1.0f;
    float* Tt = (z == 0) ? Qt : Kt;
    short* Ts = (z == 0) ? Qs : Ks;
    #pragma unroll
    for (int mi = 0; mi < 4; ++mi)
      #pragma unroll
      for (int r = 0; r < 4; ++r){
        float prt = 0.f;
        #pragma unroll
        for (int ni = 0; ni < 4; ++ni) prt += acc[mi][ni][r] * acc[mi][ni][r];
        prt += __shfl_xor(prt, 1);
        prt += __shfl_xor(prt, 2);
        prt += __shfl_xor(prt, 4);
        prt += __shfl_xor(prt, 8);
        float n = fmaxf(sqrtf(prt), 1e-7f);
        float arg = sc * n;
        float e = __expf(arg), ei = __frcp_rn(e);
        float tval = tmul * 0.5f * (e + ei) * invsc;
        float vscl = vmul * 0.5f * (e - ei) * __frcp_rn(arg);
        int grow = m0 + wm * 64 + mi * 16 + 4 * lg + r;
        int b = grow >> 11, s = grow & (S_LEN - 1);
        size_t bhs = ((size_t)(b * NH + h) * S_LEN + s);
        if (lr == 0) Tt[bhs] = tval;
        #pragma unroll
        for (int ni = 0; ni < 4; ++ni)
          Ts[bhs * DH + ni * 16 + lr] = f2bf(vscl * acc[mi][ni][r]);
      }
  } else {
    __syncthreads();                 // all waves done reading Stage
    short* vt = &Stage[0][0] + w * 4352;   // per-wave 64x68
    #pragma unroll
    for (int mi = 0; mi < 4; ++mi)
      #pragma unroll
      for (int ni = 0; ni < 4; ++ni)
        #pragma unroll
        for (int r = 0; r < 4; ++r)
          vt[(ni * 16 + lr) * 68 + mi * 16 + 4 * lg + r] = f2bf(acc[mi][ni][r]);
    int b = m0 >> 11;
    int sglob = (m0 & (S_LEN - 1)) + wm * 64;
    size_t vbase = ((size_t)(b * NH + h) * DH + lane) * S_LEN + sglob;
    #pragma unroll
    for (int j = 0; j < 8; ++j){
      s16x8 val = *(const s16x8*)&vt[lane * 68 + j * 8];
      *(s16x8*)(Vt + vbase + j * 8) = val;
    }
  }
}

// ---- K4: flash attention, IN-BLOCK key-split. Block = (bh, 32-q group); 4 waves
// each walk strided 32-key tiles with private double-buffered LDS (no barriers in
// loop, per-wave counted vmcnt); end-of-block LDS merge writes Obf directly. ----
__global__ __launch_bounds__(256, 2) void attn_kernel(const short* __restrict__ Qs,
                                                      const float* __restrict__ Qt,
                                                      const short* __restrict__ Ks,
                                                      const float* __restrict__ Kt,
                                                      const short* __restrict__ Vt,
                                                      short* __restrict__ Obf){
  __shared__ __attribute__((aligned(16))) char SMEM[66560];  // 65 KB

  int bx = blockIdx.x;
  int bh = bx & 15;                  // XCD-local heads
  int qg = 63 - (bx >> 4);           // longest first
  int tid = threadIdx.x;
  int w = tid >> 6, lane = tid & 63;
  int l5 = lane & 31, hi = lane >> 5;
  int qB = qg * 32;
  int q  = qB + l5;
  size_t bhS = (size_t)bh * S_LEN;

  // per-wave arenas
  short* Kar  = (short*)(SMEM)          + w * 4096;   // [2][32 key][64 d]
  short* Var  = (short*)(SMEM + 32768)  + w * 4096;   // [2][64 d][32 s]
  float* Ktar = (float*)(SMEM + 65536)  + w * 64;     // [2][32]

  const short* Kg  = Ks + bhS * DH;
  const short* Vg  = Vt + (size_t)bh * DH * S_LEN;
  const float* KtG = Kt + bhS;

  int srowK = lane >> 3;                               // 0..7
  int scolK = ((lane & 7) * 8) ^ (srowK << 3);
  int drV   = lane >> 2;                               // 0..15
  int gsV   = ((lane & 3) * 8) ^ ((drV & 3) << 3);

  // Q fragments (B operand: col=q=l5, k(d)=8*hi+j) — same for all waves
  s16x8 qf[4];
  #pragma unroll
  for (int dblk = 0; dblk < 4; ++dblk)
    qf[dblk] = *(const s16x8*)(Qs + (bhS + q) * DH + dblk * 16 + hi * 8);
  float aqt = Qt[bhS + q];

  fx16 acc0, acc1;
  #pragma unroll
  for (int i = 0; i < 16; ++i){ acc0[i] = 0.f; acc1[i] = 0.f; }
  float mrun = 0.f, lrun = 0.f;

  int nt = qg + 1;                   // 32-key tiles 0..qg

  // 9 VMEM issues per tile (4 K + 4 V + 1 Kt)
  #define STG(kb_, b_) { \
    _Pragma("unroll") \
    for (int i_ = 0; i_ < 4; ++i_) \
      GLL16(Kg + (size_t)((kb_) + 8 * i_ + srowK) * DH + scolK, Kar + (b_) * 2048 + i_ * 512); \
    _Pragma("unroll") \
    for (int i_ = 0; i_ < 4; ++i_) \
      GLL16(Vg + (size_t)(16 * i_ + drV) * S_LEN + (kb_) + gsV, Var + (b_) * 2048 + i_ * 512); \
    if (lane < 32) GLL4(KtG + (kb_) + lane, Ktar + (b_) * 32); }

  if (w < nt)     STG(32 * w, 0);
  if (w + 4 < nt) STG(32 * (w + 4), 1);

  int pb = 0;
  for (int t = w; t < nt; t += 4){
    if (t + 4 < nt) asm volatile("s_waitcnt vmcnt(9)" ::: "memory");
    else            asm volatile("s_waitcnt vmcnt(0)" ::: "memory");
    int buf = pb;
    int kb = 32 * t;

    // ---- QK^T (swapped): S^T[32 k][32 q] ----
    fx16 st;
    #pragma unroll
    for (int i = 0; i < 16; ++i) st[i] = 0.f;
    __builtin_amdgcn_s_setprio(1);
    const short* kbp = Kar + buf * 2048;
    #pragma unroll
    for (int dblk = 0; dblk < 4; ++dblk){
      s16x8 kf = *(const s16x8*)(kbp + l5 * 64 + ((16 * dblk + 8 * hi) ^ ((l5 & 7) << 3)));
      st = mfma32(kf, qf[dblk], st);
    }
    __builtin_amdgcn_s_setprio(0);

    // ---- rank-1 Lorentz time term + causal mask (last tile only) ----
    float p[16];
    #pragma unroll
    for (int m4 = 0; m4 < 4; ++m4){
      fx4 kt4 = *(const fx4*)(Ktar + buf * 32 + 8 * m4 + 4 * hi);
      #pragma unroll
      for (int tt = 0; tt < 4; ++tt)
        p[4 * m4 + tt] = st[4 * m4 + tt] + aqt * kt4[tt];
    }
    if (t == qg){
      #pragma unroll
      for (int r = 0; r < 16; ++r){
        int kg2 = kb + (r & 3) + 8 * (r >> 2) + 4 * hi;
        if (kg2 > q) p[r] = -3e38f;
      }
    }

    // ---- online softmax (32 keys: 16 in-lane + partner via shfl 32) ----
    float v8[8];
    #pragma unroll
    for (int i = 0; i < 8; ++i) v8[i] = fmaxf(p[i], p[i + 8]);
    #pragma unroll
    for (int i = 0; i < 4; ++i) v8[i] = fmaxf(v8[i], v8[i + 4]);
    float pmax = fmaxf(fmaxf(v8[0], v8[1]), fmaxf(v8[2], v8[3]));
    pmax = fmaxf(pmax, __shfl_xor(pmax, 32));
    if (!__all(pmax <= mrun + 8.f)){
      float mnew = fmaxf(mrun, pmax);
      float scl = __builtin_amdgcn_exp2f(mrun - mnew);
      mrun = mnew;
      lrun *= scl;
      #pragma unroll
      for (int i = 0; i < 16; ++i){ acc0[i] *= scl; acc1[i] *= scl; }
    }
    float sm[8];
    #pragma unroll
    for (int i = 0; i < 8; ++i){
      p[i]     = __builtin_amdgcn_exp2f(p[i] - mrun);
      p[i + 8] = __builtin_amdgcn_exp2f(p[i + 8] - mrun);
      sm[i] = p[i] + p[i + 8];
    }
    #pragma unroll
    for (int i = 0; i < 4; ++i) sm[i] += sm[i + 4];
    float rsum = (sm[0] + sm[1]) + (sm[2] + sm[3]);
    rsum += __shfl_xor(rsum, 32);
    lrun += rsum;

    // ---- pack P to bf16 B-fragments + PV ----
    #pragma unroll
    for (int hb = 0; hb < 2; ++hb){
      int w0 = cvtpk(p[8 * hb + 0], p[8 * hb + 1]);
      int w1 = cvtpk(p[8 * hb + 2], p[8 * hb + 3]);
      int w2 = cvtpk(p[8 * hb + 4], p[8 * hb + 5]);
      int w3 = cvtpk(p[8 * hb + 6], p[8 * hb + 7]);
      int sdA = hi ? w0 : w2;
      int sdB = hi ? w1 : w3;
      int rcA = __shfl_xor(sdA, 32);
      int rcB = __shfl_xor(sdB, 32);
      ix4 fw;
      fw.x = hi ? rcA : w0; fw.y = hi ? rcB : w1;
      fw.z = hi ? w2 : rcA; fw.w = hi ? w3 : rcB;
      s16x8 pf = __builtin_bit_cast(s16x8, fw);
      const short* vb0 = Var + buf * 2048 + l5 * 32 + ((16 * hb + 8 * hi) ^ ((l5 & 3) << 3));
      const short* vb1 = vb0 + 32 * 32;
      s16x8 vf0 = *(const s16x8*)vb0;
      s16x8 vf1 = *(const s16x8*)vb1;
      __builtin_amdgcn_s_setprio(1);
      acc0 = mfma32(vf0, pf, acc0);
      acc1 = mfma32(vf1, pf, acc1);
      __builtin_amdgcn_s_setprio(0);
    }

    if (t + 8 < nt) STG(32 * (t + 8), buf);
    pb ^= 1;
  }
  #undef STG

  // ---- in-block merge of 4 wave-partials (weights e^{m_w - M} cancel M) ----
  float* Mw   = (float*)(SMEM);            // [4][32]
  float* Lw   = (float*)(SMEM + 512);      // [4][32]
  float* Oacc = (float*)(SMEM + 1024);     // [4][32][68]
  __syncthreads();                          // all waves done with K/V arenas
  if (hi == 0){ Mw[w * 32 + l5] = mrun; Lw[w * 32 + l5] = lrun; }
  __syncthreads();
  float M = fmaxf(fmaxf(Mw[l5], Mw[32 + l5]), fmaxf(Mw[64 + l5], Mw[96 + l5]));
  float D = __builtin_amdgcn_exp2f(Mw[l5]      - M) * Lw[l5]
          + __builtin_amdgcn_exp2f(Mw[32 + l5] - M) * Lw[32 + l5]
          + __builtin_amdgcn_exp2f(Mw[64 + l5] - M) * Lw[64 + l5]
          + __builtin_amdgcn_exp2f(Mw[96 + l5] - M) * Lw[96 + l5];
  float swt = __builtin_amdgcn_exp2f(mrun - M) / D;
  float* Or = Oacc + (w * 32 + l5) * 68;
  #pragma unroll
  for (int m4 = 0; m4 < 4; ++m4){
    fx4 v0, v1;
    #pragma unroll
    for (int i = 0; i < 4; ++i){ v0[i] = acc0[4 * m4 + i] * swt; v1[i] = acc1[4 * m4 + i] * swt; }
    *(fx4*)(Or + 8 * m4 + 4 * hi)      = v0;
    *(fx4*)(Or + 32 + 8 * m4 + 4 * hi) = v1;
  }
  __syncthreads();
  int qq2 = tid >> 3;            // 0..31
  int d0  = (tid & 7) * 8;
  float o[8];
  #pragma unroll
  for (int i = 0; i < 8; ++i)
    o[i] = Oacc[(qq2) * 68 + d0 + i] + Oacc[(32 + qq2) * 68 + d0 + i]
         + Oacc[(64 + qq2) * 68 + d0 + i] + Oacc[(96 + qq2) * 68 + d0 + i];
  ix4 pkw;
  pkw.x = cvtpk(o[0], o[1]); pkw.y = cvtpk(o[2], o[3]);
  pkw.z = cvtpk(o[4], o[5]); pkw.w = cvtpk(o[6], o[7]);
  int bb = bh >> 3, hh = bh & 7;
  *(ix4*)(Obf + ((size_t)bb * S_LEN + qB + qq2) * DM + hh * DH + d0) = pkw;
}

// ---- K5: O-projection GEMM, 64x64 tiles, single-barrier loop ----
__global__ __launch_bounds__(256, 4) void gemm_o_kernel(const short* __restrict__ A,
                                                        const short* __restrict__ Bt,
                                                        float* __restrict__ C){
  __shared__ __attribute__((aligned(16))) short Asm[2][64 * 64];
  __shared__ __attribute__((aligned(16))) short Bsm[2][64 * 64];
  const int K = DM;
  int n0 = blockIdx.y * 64, m0 = blockIdx.x * 64;
  int t = threadIdx.x;
  int w = t >> 6, lane = t & 63;
  int wm = w >> 1, wn = w & 1;
  int lg = lane >> 4, lr = lane & 15;

  int aoff[2]; const short* asrcp[2];
  int boff[2]; const short* bsrcp[2];
  #pragma unroll
  for (int j = 0; j < 2; ++j){
    int ch = t + 256 * j;
    int r = ch >> 3, c = ch & 7;
    aoff[j] = ch * 8;
    asrcp[j] = A + (size_t)(m0 + r) * K + 8 * (c ^ (r & 7));
    boff[j] = ch * 8;
    bsrcp[j] = Bt + (size_t)(n0 + r) * K + 8 * (c ^ (r & 7));
  }

  {
    short* ab = &Asm[0][0]; short* bb = &Bsm[0][0];
    #pragma unroll
    for (int j = 0; j < 2; ++j){ GLL16(asrcp[j], ab + aoff[j]); GLL16(bsrcp[j], bb + boff[j]); }
  }

  fx4 acc[2][2] = {};
  for (int ks = 0; ks < 8; ++ks){
    asm volatile("s_waitcnt vmcnt(0)" ::: "memory");
    __builtin_amdgcn_s_barrier();
    if (ks < 7){
      int nb = (ks + 1) & 1;
      short* ab = &Asm[nb][0]; short* bb = &Bsm[nb][0];
      int kk = (ks + 1) * 64;
      #pragma unroll
      for (int j = 0; j < 2; ++j){ GLL16(asrcp[j] + kk, ab + aoff[j]); GLL16(bsrcp[j] + kk, bb + boff[j]); }
    }
    int buf = ks & 1;
    s16x8 af[2][2], bf[2][2];
    #pragma unroll
    for (int mi = 0; mi < 2; ++mi){
      int row = wm * 32 + mi * 16 + lr;
      #pragma unroll
      for (int s = 0; s < 2; ++s)
        af[mi][s] = *(const s16x8*)&Asm[buf][row * 64 + ((4 * s + lg) ^ (row & 7)) * 8];
    }
    #pragma unroll
    for (int ni = 0; ni < 2; ++ni){
      int row = wn * 32 + ni * 16 + lr;
      #pragma unroll
      for (int s = 0; s < 2; ++s)
        bf[ni][s] = *(const s16x8*)&Bsm[buf][row * 64 + ((4 * s + lg) ^ (row & 7)) * 8];
    }
    __builtin_amdgcn_s_setprio(1);
    #pragma unroll
    for (int s = 0; s < 2; ++s)
      #pragma unroll
      for (int mi = 0; mi < 2; ++mi)
        #pragma unroll
        for (int ni = 0; ni < 2; ++ni)
          acc[mi][ni] = mfma16(af[mi][s], bf[ni][s], acc[mi][ni]);
    __builtin_amdgcn_s_setprio(0);
  }

  #pragma unroll
  for (int mi = 0; mi < 2; ++mi)
    #pragma unroll
    for (int ni = 0; ni < 2; ++ni)
      #pragma unroll
      for (int r = 0; r < 4; ++r){
        int row = m0 + wm * 32 + mi * 16 + 4 * lg + r;
        int col = n0 + wn * 32 + ni * 16 + lr;
        C[(size_t)row * DM + col] = acc[mi][ni][r];
      }
}

extern "C" void kernel_launch(void* const* d_in, const int* in_sizes, int n_in,
                              void* d_out, int out_size, void* d_ws, size_t ws_size,
                              hipStream_t stream) {
  const float* x     = (const float*)d_in[0];
  const float* Wq    = (const float*)d_in[1];
  const float* Wk    = (const float*)d_in[2];
  const float* Wv    = (const float*)d_in[3];
  const float* Wo    = (const float*)d_in[4];
  const float* labsK = (const float*)d_in[5];

  char* w = (char*)d_ws;
  short* Wt    = (short*)(w);                                  // 2 MB
  short* xeu   = (short*)(w + (2ull  << 20));                  // 4 MB
  short* Qs    = (short*)(w + (30ull << 20));                  // 4 MB
  short* Ks    = (short*)(w + (34ull << 20));                  // 4 MB
  short* Vt    = (short*)(w + (38ull << 20));                  // 4 MB
  float* Qt    = (float*)(w + (42ull << 20));                  // 128 KB
  float* Kt    = (float*)(w + (42ull << 20) + (128ull << 10)); // 128 KB
  short* Obf   = (short*)(w + (42ull << 20) + (256ull << 10)); // 4 MB

  prep_kernel<<<dim3(512), 256, 0, stream>>>(Wq, Wk, Wv, Wo, Wt, x, xeu);

  gemm_fused_kernel<<<dim3(32, 4, 3), 256, 0, stream>>>(
      xeu, Wt, labsK, Qt, Qs, Kt, Ks, Vt);

  attn_kernel<<<dim3(1024), 256, 0, stream>>>(Qs, Qt, Ks, Kt, Vt, Obf);

  gemm_o_kernel<<<dim3(64, 8), 256, 0, stream>>>(Obf, Wt + 3 * DM * DM, (float*)d_out);
}